// Round 7
// baseline (195.194 us; speedup 1.0000x reference)
//
#include <hip/hip_runtime.h>

typedef float f32x4 __attribute__((ext_vector_type(4)));
typedef float f32x16 __attribute__((ext_vector_type(16)));
typedef _Float16 half8 __attribute__((ext_vector_type(8)));
typedef _Float16 half2v __attribute__((ext_vector_type(2)));
typedef unsigned u32x4 __attribute__((ext_vector_type(4)));

__device__ __forceinline__ unsigned f2mono(float f) {
  unsigned u = __float_as_uint(f);
  return (u & 0x80000000u) ? ~u : (u | 0x80000000u);
}
__device__ __forceinline__ float mono2f(unsigned u) {
  return (u & 0x80000000u) ? __uint_as_float(u & 0x7fffffffu) : __uint_as_float(~u);
}
__device__ __forceinline__ float lrelu(float x) { return fmaxf(x, 0.2f * x); }
__device__ __forceinline__ unsigned pkrtz(float a, float b) {
  return __builtin_bit_cast(unsigned, __builtin_amdgcn_cvt_pkrtz(a, b));
}
// packed lrelu on a cvt_pkrtz pair: v_pk_mul_f16 + v_pk_max_f16
__device__ __forceinline__ unsigned lrelu_pk(float a, float b) {
  const half2v v = __builtin_bit_cast(half2v, pkrtz(a, b));
  const half2v s = v * (half2v){(_Float16)0.2f, (_Float16)0.2f};
  return __builtin_bit_cast(unsigned, __builtin_elementwise_max(v, s));
}
__device__ __forceinline__ half8 ash8(u32x4 u) { return __builtin_bit_cast(half8, u); }
// 16-value max shaped for v_max3_f32 fusion: 5+2+1 = 8 ops
__device__ __forceinline__ float max16(const f32x16& a) {
  const float m1 = fmaxf(fmaxf(a[0], a[1]), a[2]);
  const float m2 = fmaxf(fmaxf(a[3], a[4]), a[5]);
  const float m3 = fmaxf(fmaxf(a[6], a[7]), a[8]);
  const float m4 = fmaxf(fmaxf(a[9], a[10]), a[11]);
  const float m5 = fmaxf(fmaxf(a[12], a[13]), a[14]);
  return fmaxf(fmaxf(fmaxf(m1, m2), m3), fmaxf(fmaxf(m4, m5), a[15]));
}

// ---------------- init: global_feats = mono(-1e9) ----------------
__global__ void sc_init(unsigned* __restrict__ gf, int total4) {
  int i = blockIdx.x * blockDim.x + threadIdx.x;
  if (i < total4) {
    unsigned m = f2mono(-1.0e9f);
    ((uint4*)gf)[i] = make_uint4(m, m, m, m);
  }
}

// ---- fused: gather + L1(fp16 x-split MFMA) + L2(fp16 MFMA) + running seg-max ----
// Wave owns one contiguous chunk; inputs software-pipelined one tile ahead
// (bidx/muons at iter top, dependent cond gather after layer1) to bury the
// serial load->gather->compute latency chain under compute.
// __launch_bounds__(256,2): pins the allocator at its natural no-spill size
// (R4/R6: VGPR 108-128). Default or (256,4) go occupancy-greedy => VGPR 64 =>
// 0.9-2.3 GB scratch traffic (R3/R5). Do not remove.
__global__ __launch_bounds__(256, 2) void sc_main(
    const float* __restrict__ muons, const int* __restrict__ bidx,
    const float* __restrict__ cond, const float* __restrict__ W1,
    const float* __restrict__ b1, const float* __restrict__ W2,
    const float* __restrict__ b2, unsigned* __restrict__ gf, int N, int CPW) {
  __shared__ __align__(16) _Float16 w2f[8192];  // [kc=8][j2=128][e=8] blocked
  __shared__ __align__(16) _Float16 w1e[1024];  // [kc=2][j=64][e=8]: k'=0-6 W1h,7-13 W1h(xl),14 b1h,15 b1l

  const int t = threadIdx.x;
  const int w = t >> 6;
  const int lane = t & 63;
  const int col = lane & 31;
  const int kh2 = lane >> 5;

  // ---- one-time weight staging ----
  {
    const int j = t & 127, kh = t >> 7;
    for (int kk = 0; kk < 32; ++kk) {
      const int k = kh * 32 + kk;
      w2f[((k >> 3) * 128 + j) * 8 + (k & 7)] = (_Float16)W2[k * 128 + j];
    }
  }
  if (t < 128) {
    const int j = t & 63, kc = t >> 6;
    for (int e = 0; e < 8; ++e) {
      const int kp = kc * 8 + e;
      float val;
      if (kp < 7)       val = W1[kp * 64 + j];
      else if (kp < 14) val = W1[(kp - 7) * 64 + j];
      else if (kp == 14) val = b1[j];
      else { const float b = b1[j]; val = b - (float)(_Float16)b; }
      w1e[(kc * 64 + j) * 8 + e] = (_Float16)val;
    }
  }
  __syncthreads();

  float b2v[4];
  #pragma unroll
  for (int jt = 0; jt < 4; ++jt) b2v[jt] = b2[jt * 32 + col];
  f32x16 zf;
  #pragma unroll
  for (int e = 0; e < 16; ++e) zf[e] = 0.0f;

  // ---- chunk setup ----
  const int gwave = blockIdx.x * 4 + w;
  const int start = gwave * CPW;
  if (start >= N) return;
  const int end = min(start + CPW, N);
  const int prevb = (start == 0) ? -1 : bidx[start - 1];
  const int nextb = (end >= N) ? -1 : bidx[end];
  int run_b = bidx[start];
  float run_s[4];
  #pragma unroll
  for (int jt = 0; jt < 4; ++jt) run_s[jt] = -3.0e38f;

  auto FLUSH = [&](int b, const float* m) {
    const bool interior = (b != prevb) && (b != nextb);
    if (lane < 32) {
      #pragma unroll
      for (int jt = 0; jt < 4; ++jt) {
        if (m[jt] > -2.9e38f) {
          const unsigned enc = f2mono(lrelu(m[jt] + b2v[jt]));
          unsigned* addr = &gf[b * 128 + jt * 32 + col];
          if (interior) *addr = enc; else atomicMax(addr, enc);
        }
      }
    }
  };

  // ---- input pipeline prologue (tile 0) ----
  {
    const int pc0 = min(start + col, N - 1);
    // fallthrough into loop-carried prefetch registers
    // (loads issued here, consumed in iteration 0)
  }
  int pc_n = min(start + col, N - 1);
  int bi_n = bidx[pc_n];
  float mu0_n = muons[pc_n * 3 + 0];
  float mu1_n = muons[pc_n * 3 + 1];
  float mu2_n = muons[pc_n * 3 + 2];
  f32x4 c4_n = *(const f32x4*)&cond[bi_n * 4];

  for (int pbase = start; pbase < end; pbase += 32) {
    // consume prefetched inputs
    const int bi = bi_n;
    const float mu0 = mu0_n, mu1 = mu1_n, mu2 = mu2_n;
    const f32x4 c4 = c4_n;

    // issue next tile's independent loads NOW (covered by this tile's compute)
    const int pn = min(pbase + 32 + col, N - 1);
    bi_n = bidx[pn];
    mu0_n = muons[pn * 3 + 0];
    mu1_n = muons[pn * 3 + 1];
    mu2_n = muons[pn * 3 + 2];

    // ---- fp16 2-term decompose of x ----
    float in[7];
    in[0] = mu0; in[1] = mu1; in[2] = mu2;
    in[3] = c4.x; in[4] = c4.y; in[5] = c4.z; in[6] = c4.w;

    const unsigned pA0 = pkrtz(in[0], in[1]);
    const unsigned pA1 = pkrtz(in[2], in[3]);
    const unsigned pA2 = pkrtz(in[4], in[5]);
    const half2v hA0 = __builtin_bit_cast(half2v, pA0);
    const half2v hA1 = __builtin_bit_cast(half2v, pA1);
    const half2v hA2 = __builtin_bit_cast(half2v, pA2);
    const float xl0 = in[0] - (float)hA0[0];
    const unsigned pA3 = pkrtz(in[6], xl0);          // (xh6, xl0)
    const half2v hA3 = __builtin_bit_cast(half2v, pA3);
    const float xl1 = in[1] - (float)hA0[1];
    const float xl2 = in[2] - (float)hA1[0];
    const float xl3 = in[3] - (float)hA1[1];
    const float xl4 = in[4] - (float)hA2[0];
    const float xl5 = in[5] - (float)hA2[1];
    const float xl6 = in[6] - (float)hA3[0];
    const unsigned pB0 = pkrtz(xl1, xl2);
    const unsigned pB1 = pkrtz(xl3, xl4);
    const unsigned pB2 = pkrtz(xl5, xl6);
    const unsigned pB3 = 0x3C003C00u;                // (1.0, 1.0) -> bias slots
    u32x4 bu;
    bu[0] = kh2 ? pB0 : pA0;
    bu[1] = kh2 ? pB1 : pA1;
    bu[2] = kh2 ? pB2 : pA2;
    bu[3] = kh2 ? pB3 : pA3;
    const half8 bfr = ash8(bu);

    // ---- layer1: D1[j 0..63][p], bias folded; 2 MFMAs ----
    const half8 a1lo = *(const half8*)&w1e[(kh2 * 64 + col) * 8];
    const half8 a1hi = *(const half8*)&w1e[(kh2 * 64 + 32 + col) * 8];
    const f32x16 acc0 = __builtin_amdgcn_mfma_f32_32x32x16_f16(a1lo, bfr, zf, 0, 0, 0);
    const f32x16 acc1 = __builtin_amdgcn_mfma_f32_32x32x16_f16(a1hi, bfr, zf, 0, 0, 0);

    // dependent cond gather for next tile: bi_n has arrived by now
    c4_n = *(const f32x4*)&cond[bi_n * 4];

    // ---- packed-fp16 lrelu+pack: v_pk_mul+v_pk_max on cvt_pkrtz pairs ----
    unsigned pk0[8], pk1[8];
    #pragma unroll
    for (int q = 0; q < 4; ++q) {
      pk0[2 * q]     = lrelu_pk(acc0[4 * q],     acc0[4 * q + 1]);
      pk0[2 * q + 1] = lrelu_pk(acc0[4 * q + 2], acc0[4 * q + 3]);
      pk1[2 * q]     = lrelu_pk(acc1[4 * q],     acc1[4 * q + 1]);
      pk1[2 * q + 1] = lrelu_pk(acc1[4 * q + 2], acc1[4 * q + 3]);
    }

    // ---- layer2: A-frag via half-wave exchange; 16 MFMAs ----
    f32x16 acc2[4];
    #pragma unroll
    for (int ks = 0; ks < 4; ++ks) {
      const unsigned* s = (ks < 2) ? pk0 : pk1;
      const int base = (ks & 1) * 4;
      const unsigned send0 = kh2 ? s[base + 0] : s[base + 2];
      const unsigned send1 = kh2 ? s[base + 1] : s[base + 3];
      const unsigned recv0 = (unsigned)__shfl_xor((int)send0, 32);
      const unsigned recv1 = (unsigned)__shfl_xor((int)send1, 32);
      u32x4 au;
      au[0] = kh2 ? recv0 : s[base + 0];
      au[1] = kh2 ? recv1 : s[base + 1];
      au[2] = kh2 ? s[base + 2] : recv0;
      au[3] = kh2 ? s[base + 3] : recv1;
      const half8 A = ash8(au);
      const int kcb = (2 * ks + kh2) * 128;
      #pragma unroll
      for (int jt = 0; jt < 4; ++jt) {
        const half8 B = *(const half8*)&w2f[(kcb + jt * 32 + col) * 8];
        acc2[jt] = __builtin_amdgcn_mfma_f32_32x32x16_f16(A, B, (ks == 0) ? zf : acc2[jt], 0, 0, 0);
      }
    }

    // ---- running segmented max (bias+lrelu deferred to flush) ----
    const int bA = __shfl(bi, 0);
    const int bB = __shfl(bi, 31);
    if (bA != run_b) {
      FLUSH(run_b, run_s);
      #pragma unroll
      for (int jt = 0; jt < 4; ++jt) run_s[jt] = -3.0e38f;
      run_b = bA;
    }
    if (bA == bB) {
      #pragma unroll
      for (int jt = 0; jt < 4; ++jt) {
        float m = max16(acc2[jt]);
        m = fmaxf(m, __shfl_xor(m, 32));
        run_s[jt] = fmaxf(run_s[jt], m);
      }
    } else {
      int pbi[16];
      #pragma unroll
      for (int r = 0; r < 16; ++r) {
        const int rr = (r & 3) + ((r >> 2) << 3) + (kh2 << 2);
        pbi[r] = __shfl(bi, rr);
      }
      for (int b = bA; b <= bB; ++b) {
        float m[4];
        #pragma unroll
        for (int jt = 0; jt < 4; ++jt) {
          float mm = -3.0e38f;
          #pragma unroll
          for (int r = 0; r < 16; ++r)
            if (pbi[r] == b) mm = fmaxf(mm, acc2[jt][r]);
          mm = fmaxf(mm, __shfl_xor(mm, 32));
          if (b == bA) mm = fmaxf(mm, run_s[jt]);
          m[jt] = mm;
        }
        if (b < bB) {
          FLUSH(b, m);
        } else {
          #pragma unroll
          for (int jt = 0; jt < 4; ++jt) run_s[jt] = m[jt];
        }
      }
      run_b = bB;
    }
  }
  FLUSH(run_b, run_s);
}

// ---------------- decision MLP: [B,132] @ W3 -> lrelu -> @ W4 + b4 ----------------
__global__ __launch_bounds__(128) void sc_final(
    const unsigned* __restrict__ gf, const float* __restrict__ cond,
    const float* __restrict__ W3, const float* __restrict__ b3,
    const float* __restrict__ W4, const float* __restrict__ b4,
    float* __restrict__ out, int B) {
  __shared__ __align__(16) float w3t[128 * 132];  // [j][k]
  __shared__ float b3s[128], w4s[128];
  __shared__ __align__(16) float din[8 * 132];
  __shared__ float wred[16];
  const int t = threadIdx.x;
  for (int k = 0; k < 132; ++k) w3t[t * 132 + k] = W3[k * 128 + t];
  b3s[t] = b3[t];
  w4s[t] = W4[t];
  __syncthreads();

  const int nocts = (B + 7) >> 3;
  for (int oc = blockIdx.x; oc < nocts; oc += gridDim.x) {
    const int rbase = oc << 3;
    #pragma unroll
    for (int r = 0; r < 8; ++r) {
      const int row = rbase + r;
      if (row < B) {
        din[r * 132 + t] = mono2f(gf[row * 128 + t]);
        if (t < 4) din[r * 132 + 128 + t] = cond[row * 4 + t];
      }
    }
    __syncthreads();
    float a8[8];
    #pragma unroll
    for (int r = 0; r < 8; ++r) a8[r] = b3s[t];
    for (int kg = 0; kg < 33; ++kg) {
      const f32x4 wv = *(const f32x4*)&w3t[t * 132 + kg * 4];
      #pragma unroll
      for (int r = 0; r < 8; ++r) {
        const f32x4 dv = *(const f32x4*)&din[r * 132 + kg * 4];
        a8[r] += wv[0] * dv[0] + wv[1] * dv[1] + wv[2] * dv[2] + wv[3] * dv[3];
      }
    }
    const float w4v = w4s[t];
    #pragma unroll
    for (int r = 0; r < 8; ++r) a8[r] = lrelu(a8[r]) * w4v;
    const int lane = t & 63;
    const int wv_ = t >> 6;
    #pragma unroll
    for (int r = 0; r < 8; ++r) {
      float s = a8[r];
      s += __shfl_xor(s, 1);  s += __shfl_xor(s, 2);
      s += __shfl_xor(s, 4);  s += __shfl_xor(s, 8);
      s += __shfl_xor(s, 16); s += __shfl_xor(s, 32);
      if (lane == 0) wred[wv_ * 8 + r] = s;
    }
    __syncthreads();
    if (t < 8) {
      const int row = rbase + t;
      if (row < B) out[row] = wred[t] + wred[8 + t] + b4[0];
    }
    __syncthreads();
  }
}

extern "C" void kernel_launch(void* const* d_in, const int* in_sizes, int n_in,
                              void* d_out, int out_size, void* d_ws, size_t ws_size,
                              hipStream_t stream) {
  const float* muons = (const float*)d_in[0];
  const int* bidx = (const int*)d_in[1];
  const float* cond = (const float*)d_in[2];
  const float* W1 = (const float*)d_in[4];
  const float* b1 = (const float*)d_in[5];
  const float* W2 = (const float*)d_in[6];
  const float* b2 = (const float*)d_in[7];
  const float* W3 = (const float*)d_in[8];
  const float* b3 = (const float*)d_in[9];
  const float* W4 = (const float*)d_in[10];
  const float* b4 = (const float*)d_in[11];
  float* out = (float*)d_out;
  const int N = in_sizes[1];
  const int B = out_size;
  unsigned* gf = (unsigned*)d_ws;  // B*128 mono-encoded uints (8 MB)

  const int total4 = (B * 128) / 4;
  sc_init<<<(total4 + 255) / 256, 256, 0, stream>>>(gf, total4);

  const int nblocks = 1024;
  const int nwaves = nblocks * 4;
  const int cpw = (((N + nwaves - 1) / nwaves) + 31) & ~31;  // points per wave, ×32
  sc_main<<<nblocks, 256, 0, stream>>>(muons, bidx, cond, W1, b1, W2, b2, gf, N, cpw);
  sc_final<<<256, 128, 0, stream>>>(gf, cond, W3, b3, W4, b4, out, B);
  (void)n_in; (void)ws_size;
}

// Round 8
// 154.581 us; speedup vs baseline: 1.2627x; 1.2627x over previous
//
#include <hip/hip_runtime.h>

typedef float f32x4 __attribute__((ext_vector_type(4)));
typedef float f32x16 __attribute__((ext_vector_type(16)));
typedef _Float16 half8 __attribute__((ext_vector_type(8)));
typedef _Float16 half2v __attribute__((ext_vector_type(2)));
typedef unsigned u32x4 __attribute__((ext_vector_type(4)));

__device__ __forceinline__ unsigned f2mono(float f) {
  unsigned u = __float_as_uint(f);
  return (u & 0x80000000u) ? ~u : (u | 0x80000000u);
}
__device__ __forceinline__ float mono2f(unsigned u) {
  return (u & 0x80000000u) ? __uint_as_float(u & 0x7fffffffu) : __uint_as_float(~u);
}
__device__ __forceinline__ float lrelu(float x) { return fmaxf(x, 0.2f * x); }
__device__ __forceinline__ unsigned pkrtz(float a, float b) {
  return __builtin_bit_cast(unsigned, __builtin_amdgcn_cvt_pkrtz(a, b));
}
// packed lrelu on a cvt_pkrtz pair: v_pk_mul_f16 + v_pk_max_f16
__device__ __forceinline__ unsigned lrelu_pk(float a, float b) {
  const half2v v = __builtin_bit_cast(half2v, pkrtz(a, b));
  const half2v s = v * (half2v){(_Float16)0.2f, (_Float16)0.2f};
  return __builtin_bit_cast(unsigned, __builtin_elementwise_max(v, s));
}
__device__ __forceinline__ half8 ash8(u32x4 u) { return __builtin_bit_cast(half8, u); }
// 16-value max shaped for v_max3_f32 fusion
__device__ __forceinline__ float max16(const f32x16& a) {
  const float m1 = fmaxf(fmaxf(a[0], a[1]), a[2]);
  const float m2 = fmaxf(fmaxf(a[3], a[4]), a[5]);
  const float m3 = fmaxf(fmaxf(a[6], a[7]), a[8]);
  const float m4 = fmaxf(fmaxf(a[9], a[10]), a[11]);
  const float m5 = fmaxf(fmaxf(a[12], a[13]), a[14]);
  return fmaxf(fmaxf(fmaxf(m1, m2), m3), fmaxf(fmaxf(m4, m5), a[15]));
}
// v_permlane32_swap_b32: x' = {x.lo, y.lo}, y' = {x.hi, y.hi} (lane halves)
__device__ __forceinline__ void plswap(unsigned& x, unsigned& y) {
  asm volatile("v_permlane32_swap_b32 %0, %1" : "+v"(x), "+v"(y));
}

// ---------------- init: global_feats = mono(-1e9) ----------------
__global__ void sc_init(unsigned* __restrict__ gf, int total4) {
  int i = blockIdx.x * blockDim.x + threadIdx.x;
  if (i < total4) {
    unsigned m = f2mono(-1.0e9f);
    ((uint4*)gf)[i] = make_uint4(m, m, m, m);
  }
}

// ---- fused: gather + L1(fp16 x-split MFMA) + L2(fp16 MFMA) + running seg-max ----
// Wave owns one contiguous chunk; inputs software-pipelined one tile ahead.
// Inter-layer half-wave exchange via v_permlane32_swap_b32 (VALU) instead of
// ds_bpermute+cndmask.
// __launch_bounds__(256,2): pins the allocator at its natural no-spill size
// (R4/R6: VGPR 108-128). Default or (256,4) go occupancy-greedy => VGPR 64 =>
// 0.9-2.3 GB scratch traffic (R3/R5). Do not remove.
__global__ __launch_bounds__(256, 2) void sc_main(
    const float* __restrict__ muons, const int* __restrict__ bidx,
    const float* __restrict__ cond, const float* __restrict__ W1,
    const float* __restrict__ b1, const float* __restrict__ W2,
    const float* __restrict__ b2, unsigned* __restrict__ gf, int N, int CPW) {
  __shared__ __align__(16) _Float16 w2f[8192];  // [kc=8][j2=128][e=8] blocked
  __shared__ __align__(16) _Float16 w1e[1024];  // [kc=2][j=64][e=8]: k'=0-6 W1h,7-13 W1h(xl),14 b1h,15 b1l

  const int t = threadIdx.x;
  const int w = t >> 6;
  const int lane = t & 63;
  const int col = lane & 31;
  const int kh2 = lane >> 5;

  // ---- one-time weight staging ----
  {
    const int j = t & 127, kh = t >> 7;
    for (int kk = 0; kk < 32; ++kk) {
      const int k = kh * 32 + kk;
      w2f[((k >> 3) * 128 + j) * 8 + (k & 7)] = (_Float16)W2[k * 128 + j];
    }
  }
  if (t < 128) {
    const int j = t & 63, kc = t >> 6;
    for (int e = 0; e < 8; ++e) {
      const int kp = kc * 8 + e;
      float val;
      if (kp < 7)       val = W1[kp * 64 + j];
      else if (kp < 14) val = W1[(kp - 7) * 64 + j];
      else if (kp == 14) val = b1[j];
      else { const float b = b1[j]; val = b - (float)(_Float16)b; }
      w1e[(kc * 64 + j) * 8 + e] = (_Float16)val;
    }
  }
  __syncthreads();

  float b2v[4];
  #pragma unroll
  for (int jt = 0; jt < 4; ++jt) b2v[jt] = b2[jt * 32 + col];
  f32x16 zf;
  #pragma unroll
  for (int e = 0; e < 16; ++e) zf[e] = 0.0f;

  // ---- chunk setup ----
  const int gwave = blockIdx.x * 4 + w;
  const int start = gwave * CPW;
  if (start >= N) return;
  const int end = min(start + CPW, N);
  const int prevb = (start == 0) ? -1 : bidx[start - 1];
  const int nextb = (end >= N) ? -1 : bidx[end];
  int run_b = bidx[start];
  float run_s[4];
  #pragma unroll
  for (int jt = 0; jt < 4; ++jt) run_s[jt] = -3.0e38f;

  auto FLUSH = [&](int b, const float* m) {
    const bool interior = (b != prevb) && (b != nextb);
    if (lane < 32) {
      #pragma unroll
      for (int jt = 0; jt < 4; ++jt) {
        if (m[jt] > -2.9e38f) {
          const unsigned enc = f2mono(lrelu(m[jt] + b2v[jt]));
          unsigned* addr = &gf[b * 128 + jt * 32 + col];
          if (interior) *addr = enc; else atomicMax(addr, enc);
        }
      }
    }
  };

  // ---- input pipeline prologue (tile 0) ----
  int pc_n = min(start + col, N - 1);
  int bi_n = bidx[pc_n];
  float mu0_n = muons[pc_n * 3 + 0];
  float mu1_n = muons[pc_n * 3 + 1];
  float mu2_n = muons[pc_n * 3 + 2];
  f32x4 c4_n = *(const f32x4*)&cond[bi_n * 4];

  for (int pbase = start; pbase < end; pbase += 32) {
    // consume prefetched inputs
    const int bi = bi_n;
    const float mu0 = mu0_n, mu1 = mu1_n, mu2 = mu2_n;
    const f32x4 c4 = c4_n;

    // issue next tile's independent loads NOW (covered by this tile's compute)
    const int pn = min(pbase + 32 + col, N - 1);
    bi_n = bidx[pn];
    mu0_n = muons[pn * 3 + 0];
    mu1_n = muons[pn * 3 + 1];
    mu2_n = muons[pn * 3 + 2];

    // ---- fp16 2-term decompose of x ----
    float in[7];
    in[0] = mu0; in[1] = mu1; in[2] = mu2;
    in[3] = c4.x; in[4] = c4.y; in[5] = c4.z; in[6] = c4.w;

    const unsigned pA0 = pkrtz(in[0], in[1]);
    const unsigned pA1 = pkrtz(in[2], in[3]);
    const unsigned pA2 = pkrtz(in[4], in[5]);
    const half2v hA0 = __builtin_bit_cast(half2v, pA0);
    const half2v hA1 = __builtin_bit_cast(half2v, pA1);
    const half2v hA2 = __builtin_bit_cast(half2v, pA2);
    const float xl0 = in[0] - (float)hA0[0];
    const unsigned pA3 = pkrtz(in[6], xl0);          // (xh6, xl0)
    const half2v hA3 = __builtin_bit_cast(half2v, pA3);
    const float xl1 = in[1] - (float)hA0[1];
    const float xl2 = in[2] - (float)hA1[0];
    const float xl3 = in[3] - (float)hA1[1];
    const float xl4 = in[4] - (float)hA2[0];
    const float xl5 = in[5] - (float)hA2[1];
    const float xl6 = in[6] - (float)hA3[0];
    const unsigned pB0 = pkrtz(xl1, xl2);
    const unsigned pB1 = pkrtz(xl3, xl4);
    const unsigned pB2 = pkrtz(xl5, xl6);
    const unsigned pB3 = 0x3C003C00u;                // (1.0, 1.0) -> bias slots
    u32x4 bu;
    bu[0] = kh2 ? pB0 : pA0;
    bu[1] = kh2 ? pB1 : pA1;
    bu[2] = kh2 ? pB2 : pA2;
    bu[3] = kh2 ? pB3 : pA3;
    const half8 bfr = ash8(bu);

    // ---- layer1: D1[j 0..63][p], bias folded; 2 MFMAs ----
    const half8 a1lo = *(const half8*)&w1e[(kh2 * 64 + col) * 8];
    const half8 a1hi = *(const half8*)&w1e[(kh2 * 64 + 32 + col) * 8];
    const f32x16 acc0 = __builtin_amdgcn_mfma_f32_32x32x16_f16(a1lo, bfr, zf, 0, 0, 0);
    const f32x16 acc1 = __builtin_amdgcn_mfma_f32_32x32x16_f16(a1hi, bfr, zf, 0, 0, 0);

    // dependent cond gather for next tile: bi_n has arrived by now
    c4_n = *(const f32x4*)&cond[bi_n * 4];

    // ---- packed-fp16 lrelu+pack ----
    unsigned pk0[8], pk1[8];
    #pragma unroll
    for (int q = 0; q < 4; ++q) {
      pk0[2 * q]     = lrelu_pk(acc0[4 * q],     acc0[4 * q + 1]);
      pk0[2 * q + 1] = lrelu_pk(acc0[4 * q + 2], acc0[4 * q + 3]);
      pk1[2 * q]     = lrelu_pk(acc1[4 * q],     acc1[4 * q + 1]);
      pk1[2 * q + 1] = lrelu_pk(acc1[4 * q + 2], acc1[4 * q + 3]);
    }

    // ---- layer2: A-frag via v_permlane32_swap_b32; 16 MFMAs ----
    f32x16 acc2[4];
    #pragma unroll
    for (int ks = 0; ks < 4; ++ks) {
      const unsigned* s = (ks < 2) ? pk0 : pk1;
      const int base = (ks & 1) * 4;
      // au[0]={s0.lo|s2.lo}, au[2]={s0.hi|s2.hi}; same for (s1,s3) -> au[1],au[3]
      unsigned x0 = s[base + 0], y0 = s[base + 2];
      unsigned x1 = s[base + 1], y1 = s[base + 3];
      plswap(x0, y0);
      plswap(x1, y1);
      u32x4 au;
      au[0] = x0; au[1] = x1; au[2] = y0; au[3] = y1;
      const half8 A = ash8(au);
      const int kcb = (2 * ks + kh2) * 128;
      #pragma unroll
      for (int jt = 0; jt < 4; ++jt) {
        const half8 B = *(const half8*)&w2f[(kcb + jt * 32 + col) * 8];
        acc2[jt] = __builtin_amdgcn_mfma_f32_32x32x16_f16(A, B, (ks == 0) ? zf : acc2[jt], 0, 0, 0);
      }
    }

    // ---- running segmented max (bias+lrelu deferred to flush) ----
    const int bA = __shfl(bi, 0);
    const int bB = __shfl(bi, 31);
    if (bA != run_b) {
      FLUSH(run_b, run_s);
      #pragma unroll
      for (int jt = 0; jt < 4; ++jt) run_s[jt] = -3.0e38f;
      run_b = bA;
    }
    if (bA == bB) {
      #pragma unroll
      for (int jt = 0; jt < 4; ++jt) {
        float m = max16(acc2[jt]);
        m = fmaxf(m, __shfl_xor(m, 32));
        run_s[jt] = fmaxf(run_s[jt], m);
      }
    } else {
      int pbi[16];
      #pragma unroll
      for (int r = 0; r < 16; ++r) {
        const int rr = (r & 3) + ((r >> 2) << 3) + (kh2 << 2);
        pbi[r] = __shfl(bi, rr);
      }
      for (int b = bA; b <= bB; ++b) {
        float m[4];
        #pragma unroll
        for (int jt = 0; jt < 4; ++jt) {
          float mm = -3.0e38f;
          #pragma unroll
          for (int r = 0; r < 16; ++r)
            if (pbi[r] == b) mm = fmaxf(mm, acc2[jt][r]);
          mm = fmaxf(mm, __shfl_xor(mm, 32));
          if (b == bA) mm = fmaxf(mm, run_s[jt]);
          m[jt] = mm;
        }
        if (b < bB) {
          FLUSH(b, m);
        } else {
          #pragma unroll
          for (int jt = 0; jt < 4; ++jt) run_s[jt] = m[jt];
        }
      }
      run_b = bB;
    }
  }
  FLUSH(run_b, run_s);
}

// ---------------- decision MLP: [B,132] @ W3 -> lrelu -> @ W4 + b4 ----------------
// Grid MUST stay ~1024: at 67.5KB LDS only 2 blocks/CU fit; 256 blocks leaves
// 2 waves/CU => latency-starved (R7: ~60us vs ~25us). Do not shrink the grid.
__global__ __launch_bounds__(128) void sc_final(
    const unsigned* __restrict__ gf, const float* __restrict__ cond,
    const float* __restrict__ W3, const float* __restrict__ b3,
    const float* __restrict__ W4, const float* __restrict__ b4,
    float* __restrict__ out, int B) {
  __shared__ __align__(16) float w3t[128 * 132];  // [j][k]
  __shared__ float b3s[128], w4s[128];
  __shared__ __align__(16) float din[8 * 132];
  __shared__ float wred[16];
  const int t = threadIdx.x;
  for (int k = 0; k < 132; ++k) w3t[t * 132 + k] = W3[k * 128 + t];
  b3s[t] = b3[t];
  w4s[t] = W4[t];
  __syncthreads();

  const int nocts = (B + 7) >> 3;
  for (int oc = blockIdx.x; oc < nocts; oc += gridDim.x) {
    const int rbase = oc << 3;
    #pragma unroll
    for (int r = 0; r < 8; ++r) {
      const int row = rbase + r;
      if (row < B) {
        din[r * 132 + t] = mono2f(gf[row * 128 + t]);
        if (t < 4) din[r * 132 + 128 + t] = cond[row * 4 + t];
      }
    }
    __syncthreads();
    float a8[8];
    #pragma unroll
    for (int r = 0; r < 8; ++r) a8[r] = b3s[t];
    for (int kg = 0; kg < 33; ++kg) {
      const f32x4 wv = *(const f32x4*)&w3t[t * 132 + kg * 4];
      #pragma unroll
      for (int r = 0; r < 8; ++r) {
        const f32x4 dv = *(const f32x4*)&din[r * 132 + kg * 4];
        a8[r] += wv[0] * dv[0] + wv[1] * dv[1] + wv[2] * dv[2] + wv[3] * dv[3];
      }
    }
    const float w4v = w4s[t];
    #pragma unroll
    for (int r = 0; r < 8; ++r) a8[r] = lrelu(a8[r]) * w4v;
    const int lane = t & 63;
    const int wv_ = t >> 6;
    #pragma unroll
    for (int r = 0; r < 8; ++r) {
      float s = a8[r];
      s += __shfl_xor(s, 1);  s += __shfl_xor(s, 2);
      s += __shfl_xor(s, 4);  s += __shfl_xor(s, 8);
      s += __shfl_xor(s, 16); s += __shfl_xor(s, 32);
      if (lane == 0) wred[wv_ * 8 + r] = s;
    }
    __syncthreads();
    if (t < 8) {
      const int row = rbase + t;
      if (row < B) out[row] = wred[t] + wred[8 + t] + b4[0];
    }
    __syncthreads();
  }
}

extern "C" void kernel_launch(void* const* d_in, const int* in_sizes, int n_in,
                              void* d_out, int out_size, void* d_ws, size_t ws_size,
                              hipStream_t stream) {
  const float* muons = (const float*)d_in[0];
  const int* bidx = (const int*)d_in[1];
  const float* cond = (const float*)d_in[2];
  const float* W1 = (const float*)d_in[4];
  const float* b1 = (const float*)d_in[5];
  const float* W2 = (const float*)d_in[6];
  const float* b2 = (const float*)d_in[7];
  const float* W3 = (const float*)d_in[8];
  const float* b3 = (const float*)d_in[9];
  const float* W4 = (const float*)d_in[10];
  const float* b4 = (const float*)d_in[11];
  float* out = (float*)d_out;
  const int N = in_sizes[1];
  const int B = out_size;
  unsigned* gf = (unsigned*)d_ws;  // B*128 mono-encoded uints (8 MB)

  const int total4 = (B * 128) / 4;
  sc_init<<<(total4 + 255) / 256, 256, 0, stream>>>(gf, total4);

  const int nblocks = 1024;
  const int nwaves = nblocks * 4;
  const int cpw = (((N + nwaves - 1) / nwaves) + 31) & ~31;  // points per wave, ×32
  sc_main<<<nblocks, 256, 0, stream>>>(muons, bidx, cond, W1, b1, W2, b2, gf, N, cpw);
  sc_final<<<1024, 128, 0, stream>>>(gf, cond, W3, b3, W4, b4, out, B);
  (void)n_in; (void)ws_size;
}

// Round 9
// 154.259 us; speedup vs baseline: 1.2654x; 1.0021x over previous
//
#include <hip/hip_runtime.h>

typedef float f32x4 __attribute__((ext_vector_type(4)));
typedef float f32x16 __attribute__((ext_vector_type(16)));
typedef _Float16 half8 __attribute__((ext_vector_type(8)));
typedef _Float16 half2v __attribute__((ext_vector_type(2)));
typedef unsigned u32x4 __attribute__((ext_vector_type(4)));

__device__ __forceinline__ unsigned f2mono(float f) {
  unsigned u = __float_as_uint(f);
  return (u & 0x80000000u) ? ~u : (u | 0x80000000u);
}
__device__ __forceinline__ float mono2f(unsigned u) {
  return (u & 0x80000000u) ? __uint_as_float(u & 0x7fffffffu) : __uint_as_float(~u);
}
__device__ __forceinline__ float lrelu(float x) { return fmaxf(x, 0.2f * x); }
__device__ __forceinline__ unsigned pkrtz(float a, float b) {
  return __builtin_bit_cast(unsigned, __builtin_amdgcn_cvt_pkrtz(a, b));
}
// packed lrelu on a cvt_pkrtz pair: v_pk_mul_f16 + v_pk_max_f16
__device__ __forceinline__ unsigned lrelu_pk(float a, float b) {
  const half2v v = __builtin_bit_cast(half2v, pkrtz(a, b));
  const half2v s = v * (half2v){(_Float16)0.2f, (_Float16)0.2f};
  return __builtin_bit_cast(unsigned, __builtin_elementwise_max(v, s));
}
__device__ __forceinline__ half8 ash8(u32x4 u) { return __builtin_bit_cast(half8, u); }
// 16-value max shaped for v_max3_f32 fusion
__device__ __forceinline__ float max16(const f32x16& a) {
  const float m1 = fmaxf(fmaxf(a[0], a[1]), a[2]);
  const float m2 = fmaxf(fmaxf(a[3], a[4]), a[5]);
  const float m3 = fmaxf(fmaxf(a[6], a[7]), a[8]);
  const float m4 = fmaxf(fmaxf(a[9], a[10]), a[11]);
  const float m5 = fmaxf(fmaxf(a[12], a[13]), a[14]);
  return fmaxf(fmaxf(fmaxf(m1, m2), m3), fmaxf(fmaxf(m4, m5), a[15]));
}
// v_permlane32_swap_b32: x' = {x.lo, y.lo}, y' = {x.hi, y.hi} (lane halves)
__device__ __forceinline__ void plswap(unsigned& x, unsigned& y) {
  asm volatile("v_permlane32_swap_b32 %0, %1" : "+v"(x), "+v"(y));
}

// ---------------- init: global_feats = mono(-1e9) ----------------
__global__ void sc_init(unsigned* __restrict__ gf, int total4) {
  int i = blockIdx.x * blockDim.x + threadIdx.x;
  if (i < total4) {
    unsigned m = f2mono(-1.0e9f);
    ((uint4*)gf)[i] = make_uint4(m, m, m, m);
  }
}

// ---- fused: gather + L1(fp16 x-split MFMA) + L2(fp16 MFMA) + running seg-max ----
// All weight fragments (W1: 2 half8, W2: 16 half8) are loop-invariant per lane:
// hoisted to registers before the K-loop (R8 showed 18 in-loop ds_read_b128 were
// the exposed-latency bottleneck at ~2 waves/SIMD). The main loop has NO LDS ops.
// __launch_bounds__(256,2): pins the allocator at its no-spill point (R4/R6/R8).
// Occupancy-greedy defaults pick VGPR 64 => 0.9-2.3 GB scratch (R3/R5). Keep.
__global__ __launch_bounds__(256, 2) void sc_main(
    const float* __restrict__ muons, const int* __restrict__ bidx,
    const float* __restrict__ cond, const float* __restrict__ W1,
    const float* __restrict__ b1, const float* __restrict__ W2,
    const float* __restrict__ b2, unsigned* __restrict__ gf, int N, int CPW) {
  __shared__ __align__(16) _Float16 w2f[8192];  // [kc=8][j2=128][e=8] blocked
  __shared__ __align__(16) _Float16 w1e[1024];  // [kc=2][j=64][e=8]: k'=0-6 W1h,7-13 W1h(xl),14 b1h,15 b1l

  const int t = threadIdx.x;
  const int w = t >> 6;
  const int lane = t & 63;
  const int col = lane & 31;
  const int kh2 = lane >> 5;

  // ---- one-time weight staging ----
  {
    const int j = t & 127, kh = t >> 7;
    for (int kk = 0; kk < 32; ++kk) {
      const int k = kh * 32 + kk;
      w2f[((k >> 3) * 128 + j) * 8 + (k & 7)] = (_Float16)W2[k * 128 + j];
    }
  }
  if (t < 128) {
    const int j = t & 63, kc = t >> 6;
    for (int e = 0; e < 8; ++e) {
      const int kp = kc * 8 + e;
      float val;
      if (kp < 7)       val = W1[kp * 64 + j];
      else if (kp < 14) val = W1[(kp - 7) * 64 + j];
      else if (kp == 14) val = b1[j];
      else { const float b = b1[j]; val = b - (float)(_Float16)b; }
      w1e[(kc * 64 + j) * 8 + e] = (_Float16)val;
    }
  }
  __syncthreads();

  float b2v[4];
  #pragma unroll
  for (int jt = 0; jt < 4; ++jt) b2v[jt] = b2[jt * 32 + col];
  f32x16 zf;
  #pragma unroll
  for (int e = 0; e < 16; ++e) zf[e] = 0.0f;

  // ---- chunk setup ----
  const int gwave = blockIdx.x * 4 + w;
  const int start = gwave * CPW;
  if (start >= N) return;
  const int end = min(start + CPW, N);
  const int prevb = (start == 0) ? -1 : bidx[start - 1];
  const int nextb = (end >= N) ? -1 : bidx[end];
  int run_b = bidx[start];
  float run_s[4];
  #pragma unroll
  for (int jt = 0; jt < 4; ++jt) run_s[jt] = -3.0e38f;

  // ---- hoist ALL weight fragments to registers (loop-invariant per lane) ----
  const half8 a1lo = *(const half8*)&w1e[(kh2 * 64 + col) * 8];
  const half8 a1hi = *(const half8*)&w1e[(kh2 * 64 + 32 + col) * 8];
  half8 Breg[4][4];
  #pragma unroll
  for (int ks = 0; ks < 4; ++ks)
    #pragma unroll
    for (int jt = 0; jt < 4; ++jt)
      Breg[ks][jt] = *(const half8*)&w2f[((2 * ks + kh2) * 128 + jt * 32 + col) * 8];

  auto FLUSH = [&](int b, const float* m) {
    const bool interior = (b != prevb) && (b != nextb);
    if (lane < 32) {
      #pragma unroll
      for (int jt = 0; jt < 4; ++jt) {
        if (m[jt] > -2.9e38f) {
          const unsigned enc = f2mono(lrelu(m[jt] + b2v[jt]));
          unsigned* addr = &gf[b * 128 + jt * 32 + col];
          if (interior) *addr = enc; else atomicMax(addr, enc);
        }
      }
    }
  };

  // ---- input pipeline prologue (tile 0) ----
  int pc_n = min(start + col, N - 1);
  int bi_n = bidx[pc_n];
  float mu0_n = muons[pc_n * 3 + 0];
  float mu1_n = muons[pc_n * 3 + 1];
  float mu2_n = muons[pc_n * 3 + 2];
  f32x4 c4_n = *(const f32x4*)&cond[bi_n * 4];

  for (int pbase = start; pbase < end; pbase += 32) {
    // consume prefetched inputs
    const int bi = bi_n;
    const float mu0 = mu0_n, mu1 = mu1_n, mu2 = mu2_n;
    const f32x4 c4 = c4_n;

    // issue next tile's independent loads NOW (covered by this tile's compute)
    const int pn = min(pbase + 32 + col, N - 1);
    bi_n = bidx[pn];
    mu0_n = muons[pn * 3 + 0];
    mu1_n = muons[pn * 3 + 1];
    mu2_n = muons[pn * 3 + 2];

    // ---- fp16 2-term decompose of x ----
    float in[7];
    in[0] = mu0; in[1] = mu1; in[2] = mu2;
    in[3] = c4.x; in[4] = c4.y; in[5] = c4.z; in[6] = c4.w;

    const unsigned pA0 = pkrtz(in[0], in[1]);
    const unsigned pA1 = pkrtz(in[2], in[3]);
    const unsigned pA2 = pkrtz(in[4], in[5]);
    const half2v hA0 = __builtin_bit_cast(half2v, pA0);
    const half2v hA1 = __builtin_bit_cast(half2v, pA1);
    const half2v hA2 = __builtin_bit_cast(half2v, pA2);
    const float xl0 = in[0] - (float)hA0[0];
    const unsigned pA3 = pkrtz(in[6], xl0);          // (xh6, xl0)
    const half2v hA3 = __builtin_bit_cast(half2v, pA3);
    const float xl1 = in[1] - (float)hA0[1];
    const float xl2 = in[2] - (float)hA1[0];
    const float xl3 = in[3] - (float)hA1[1];
    const float xl4 = in[4] - (float)hA2[0];
    const float xl5 = in[5] - (float)hA2[1];
    const float xl6 = in[6] - (float)hA3[0];
    const unsigned pB0 = pkrtz(xl1, xl2);
    const unsigned pB1 = pkrtz(xl3, xl4);
    const unsigned pB2 = pkrtz(xl5, xl6);
    const unsigned pB3 = 0x3C003C00u;                // (1.0, 1.0) -> bias slots
    u32x4 bu;
    bu[0] = kh2 ? pB0 : pA0;
    bu[1] = kh2 ? pB1 : pA1;
    bu[2] = kh2 ? pB2 : pA2;
    bu[3] = kh2 ? pB3 : pA3;
    const half8 bfr = ash8(bu);

    // ---- layer1: D1[j 0..63][p], bias folded; 2 MFMAs (A from regs) ----
    const f32x16 acc0 = __builtin_amdgcn_mfma_f32_32x32x16_f16(a1lo, bfr, zf, 0, 0, 0);
    const f32x16 acc1 = __builtin_amdgcn_mfma_f32_32x32x16_f16(a1hi, bfr, zf, 0, 0, 0);

    // dependent cond gather for next tile: bi_n has arrived by now
    c4_n = *(const f32x4*)&cond[bi_n * 4];

    // ---- packed-fp16 lrelu+pack ----
    unsigned pk0[8], pk1[8];
    #pragma unroll
    for (int q = 0; q < 4; ++q) {
      pk0[2 * q]     = lrelu_pk(acc0[4 * q],     acc0[4 * q + 1]);
      pk0[2 * q + 1] = lrelu_pk(acc0[4 * q + 2], acc0[4 * q + 3]);
      pk1[2 * q]     = lrelu_pk(acc1[4 * q],     acc1[4 * q + 1]);
      pk1[2 * q + 1] = lrelu_pk(acc1[4 * q + 2], acc1[4 * q + 3]);
    }

    // ---- layer2: A-frag via v_permlane32_swap_b32; 16 MFMAs, B from regs ----
    f32x16 acc2[4];
    #pragma unroll
    for (int ks = 0; ks < 4; ++ks) {
      const unsigned* s = (ks < 2) ? pk0 : pk1;
      const int base = (ks & 1) * 4;
      unsigned x0 = s[base + 0], y0 = s[base + 2];
      unsigned x1 = s[base + 1], y1 = s[base + 3];
      plswap(x0, y0);
      plswap(x1, y1);
      u32x4 au;
      au[0] = x0; au[1] = x1; au[2] = y0; au[3] = y1;
      const half8 A = ash8(au);
      #pragma unroll
      for (int jt = 0; jt < 4; ++jt) {
        acc2[jt] = __builtin_amdgcn_mfma_f32_32x32x16_f16(A, Breg[ks][jt],
                                                          (ks == 0) ? zf : acc2[jt], 0, 0, 0);
      }
    }

    // ---- running segmented max (bias+lrelu deferred to flush) ----
    const int bA = __shfl(bi, 0);
    const int bB = __shfl(bi, 31);
    if (bA != run_b) {
      FLUSH(run_b, run_s);
      #pragma unroll
      for (int jt = 0; jt < 4; ++jt) run_s[jt] = -3.0e38f;
      run_b = bA;
    }
    if (bA == bB) {
      #pragma unroll
      for (int jt = 0; jt < 4; ++jt) {
        float m = max16(acc2[jt]);
        m = fmaxf(m, __shfl_xor(m, 32));
        run_s[jt] = fmaxf(run_s[jt], m);
      }
    } else {
      int pbi[16];
      #pragma unroll
      for (int r = 0; r < 16; ++r) {
        const int rr = (r & 3) + ((r >> 2) << 3) + (kh2 << 2);
        pbi[r] = __shfl(bi, rr);
      }
      for (int b = bA; b <= bB; ++b) {
        float m[4];
        #pragma unroll
        for (int jt = 0; jt < 4; ++jt) {
          float mm = -3.0e38f;
          #pragma unroll
          for (int r = 0; r < 16; ++r)
            if (pbi[r] == b) mm = fmaxf(mm, acc2[jt][r]);
          mm = fmaxf(mm, __shfl_xor(mm, 32));
          if (b == bA) mm = fmaxf(mm, run_s[jt]);
          m[jt] = mm;
        }
        if (b < bB) {
          FLUSH(b, m);
        } else {
          #pragma unroll
          for (int jt = 0; jt < 4; ++jt) run_s[jt] = m[jt];
        }
      }
      run_b = bB;
    }
  }
  FLUSH(run_b, run_s);
}

// ---------------- decision MLP: [B,132] @ W3 -> lrelu -> @ W4 + b4 ----------------
// Grid MUST stay ~1024: at 67.5KB LDS only 2 blocks/CU fit; 256 blocks leaves
// 2 waves/CU => latency-starved (R7: ~60us vs ~25us). Do not shrink the grid.
__global__ __launch_bounds__(128) void sc_final(
    const unsigned* __restrict__ gf, const float* __restrict__ cond,
    const float* __restrict__ W3, const float* __restrict__ b3,
    const float* __restrict__ W4, const float* __restrict__ b4,
    float* __restrict__ out, int B) {
  __shared__ __align__(16) float w3t[128 * 132];  // [j][k]
  __shared__ float b3s[128], w4s[128];
  __shared__ __align__(16) float din[8 * 132];
  __shared__ float wred[16];
  const int t = threadIdx.x;
  for (int k = 0; k < 132; ++k) w3t[t * 132 + k] = W3[k * 128 + t];
  b3s[t] = b3[t];
  w4s[t] = W4[t];
  __syncthreads();

  const int nocts = (B + 7) >> 3;
  for (int oc = blockIdx.x; oc < nocts; oc += gridDim.x) {
    const int rbase = oc << 3;
    #pragma unroll
    for (int r = 0; r < 8; ++r) {
      const int row = rbase + r;
      if (row < B) {
        din[r * 132 + t] = mono2f(gf[row * 128 + t]);
        if (t < 4) din[r * 132 + 128 + t] = cond[row * 4 + t];
      }
    }
    __syncthreads();
    float a8[8];
    #pragma unroll
    for (int r = 0; r < 8; ++r) a8[r] = b3s[t];
    for (int kg = 0; kg < 33; ++kg) {
      const f32x4 wv = *(const f32x4*)&w3t[t * 132 + kg * 4];
      #pragma unroll
      for (int r = 0; r < 8; ++r) {
        const f32x4 dv = *(const f32x4*)&din[r * 132 + kg * 4];
        a8[r] += wv[0] * dv[0] + wv[1] * dv[1] + wv[2] * dv[2] + wv[3] * dv[3];
      }
    }
    const float w4v = w4s[t];
    #pragma unroll
    for (int r = 0; r < 8; ++r) a8[r] = lrelu(a8[r]) * w4v;
    const int lane = t & 63;
    const int wv_ = t >> 6;
    #pragma unroll
    for (int r = 0; r < 8; ++r) {
      float s = a8[r];
      s += __shfl_xor(s, 1);  s += __shfl_xor(s, 2);
      s += __shfl_xor(s, 4);  s += __shfl_xor(s, 8);
      s += __shfl_xor(s, 16); s += __shfl_xor(s, 32);
      if (lane == 0) wred[wv_ * 8 + r] = s;
    }
    __syncthreads();
    if (t < 8) {
      const int row = rbase + t;
      if (row < B) out[row] = wred[t] + wred[8 + t] + b4[0];
    }
    __syncthreads();
  }
}

extern "C" void kernel_launch(void* const* d_in, const int* in_sizes, int n_in,
                              void* d_out, int out_size, void* d_ws, size_t ws_size,
                              hipStream_t stream) {
  const float* muons = (const float*)d_in[0];
  const int* bidx = (const int*)d_in[1];
  const float* cond = (const float*)d_in[2];
  const float* W1 = (const float*)d_in[4];
  const float* b1 = (const float*)d_in[5];
  const float* W2 = (const float*)d_in[6];
  const float* b2 = (const float*)d_in[7];
  const float* W3 = (const float*)d_in[8];
  const float* b3 = (const float*)d_in[9];
  const float* W4 = (const float*)d_in[10];
  const float* b4 = (const float*)d_in[11];
  float* out = (float*)d_out;
  const int N = in_sizes[1];
  const int B = out_size;
  unsigned* gf = (unsigned*)d_ws;  // B*128 mono-encoded uints (8 MB)

  const int total4 = (B * 128) / 4;
  sc_init<<<(total4 + 255) / 256, 256, 0, stream>>>(gf, total4);

  const int nblocks = 2048;
  const int nwaves = nblocks * 4;
  const int cpw = (((N + nwaves - 1) / nwaves) + 31) & ~31;  // points per wave, ×32
  sc_main<<<nblocks, 256, 0, stream>>>(muons, bidx, cond, W1, b1, W2, b2, gf, N, cpw);
  sc_final<<<1024, 128, 0, stream>>>(gf, cond, W3, b3, W4, b4, out, B);
  (void)n_in; (void)ws_size;
}

// Round 10
// 151.357 us; speedup vs baseline: 1.2896x; 1.0192x over previous
//
#include <hip/hip_runtime.h>

typedef float f32x4 __attribute__((ext_vector_type(4)));
typedef float f32x16 __attribute__((ext_vector_type(16)));
typedef _Float16 half8 __attribute__((ext_vector_type(8)));
typedef _Float16 half2v __attribute__((ext_vector_type(2)));
typedef unsigned u32x4 __attribute__((ext_vector_type(4)));

__device__ __forceinline__ unsigned f2mono(float f) {
  unsigned u = __float_as_uint(f);
  return (u & 0x80000000u) ? ~u : (u | 0x80000000u);
}
__device__ __forceinline__ float mono2f(unsigned u) {
  return (u & 0x80000000u) ? __uint_as_float(u & 0x7fffffffu) : __uint_as_float(~u);
}
__device__ __forceinline__ float lrelu(float x) { return fmaxf(x, 0.2f * x); }
__device__ __forceinline__ unsigned pkrtz(float a, float b) {
  return __builtin_bit_cast(unsigned, __builtin_amdgcn_cvt_pkrtz(a, b));
}
// packed lrelu on a cvt_pkrtz pair: v_pk_mul_f16 + v_pk_max_f16
__device__ __forceinline__ unsigned lrelu_pk(float a, float b) {
  const half2v v = __builtin_bit_cast(half2v, pkrtz(a, b));
  const half2v s = v * (half2v){(_Float16)0.2f, (_Float16)0.2f};
  return __builtin_bit_cast(unsigned, __builtin_elementwise_max(v, s));
}
__device__ __forceinline__ half8 ash8(u32x4 u) { return __builtin_bit_cast(half8, u); }
// 16-value max shaped for v_max3_f32 fusion
__device__ __forceinline__ float max16(const f32x16& a) {
  const float m1 = fmaxf(fmaxf(a[0], a[1]), a[2]);
  const float m2 = fmaxf(fmaxf(a[3], a[4]), a[5]);
  const float m3 = fmaxf(fmaxf(a[6], a[7]), a[8]);
  const float m4 = fmaxf(fmaxf(a[9], a[10]), a[11]);
  const float m5 = fmaxf(fmaxf(a[12], a[13]), a[14]);
  return fmaxf(fmaxf(fmaxf(m1, m2), m3), fmaxf(fmaxf(m4, m5), a[15]));
}
// v_permlane32_swap_b32: x' = {x.lo, y.lo}, y' = {x.hi, y.hi} (lane halves)
__device__ __forceinline__ void plswap(unsigned& x, unsigned& y) {
  asm volatile("v_permlane32_swap_b32 %0, %1" : "+v"(x), "+v"(y));
}
// cross-half max in pure VALU: lane i gets fmax(m[i&31], m[(i&31)+32])
__device__ __forceinline__ float xhalf_max(float m) {
  unsigned a = __float_as_uint(m), b = a;
  plswap(a, b);
  return fmaxf(__uint_as_float(a), __uint_as_float(b));
}

// ---------------- init: global_feats = mono(-1e9) ----------------
__global__ void sc_init(unsigned* __restrict__ gf, int total4) {
  int i = blockIdx.x * blockDim.x + threadIdx.x;
  if (i < total4) {
    unsigned m = f2mono(-1.0e9f);
    ((uint4*)gf)[i] = make_uint4(m, m, m, m);
  }
}

// ---- fused: gather + L1(fp16 x-split MFMA) + L2(fp16 MFMA) + running seg-max ----
// Latency-bound at ~2 waves/SIMD (acc floor) => ILP: each iteration processes
// TWO 32-point tiles stage-interleaved (L1 A+B together; L2/segmax A then B,
// acc regs reused). B-fragments read from LDS in-loop (R8-validated; R9 reg
// hoist was neutral and cost occupancy). Cross-half reduces via permlane32.
// __launch_bounds__(256,2): pins allocator at no-spill point (R4/R6/R8).
// Greedy defaults pick VGPR 64 => 0.9-2.3 GB scratch (R3/R5). Keep.
__global__ __launch_bounds__(256, 2) void sc_main(
    const float* __restrict__ muons, const int* __restrict__ bidx,
    const float* __restrict__ cond, const float* __restrict__ W1,
    const float* __restrict__ b1, const float* __restrict__ W2,
    const float* __restrict__ b2, unsigned* __restrict__ gf, int N, int CPW) {
  __shared__ __align__(16) _Float16 w2f[8192];  // [kc=8][j2=128][e=8] blocked
  __shared__ __align__(16) _Float16 w1e[1024];  // [kc=2][j=64][e=8]: k'=0-6 W1h,7-13 W1h(xl),14 b1h,15 b1l

  const int t = threadIdx.x;
  const int w = t >> 6;
  const int lane = t & 63;
  const int col = lane & 31;
  const int kh2 = lane >> 5;

  // ---- one-time weight staging ----
  {
    const int j = t & 127, kh = t >> 7;
    for (int kk = 0; kk < 32; ++kk) {
      const int k = kh * 32 + kk;
      w2f[((k >> 3) * 128 + j) * 8 + (k & 7)] = (_Float16)W2[k * 128 + j];
    }
  }
  if (t < 128) {
    const int j = t & 63, kc = t >> 6;
    for (int e = 0; e < 8; ++e) {
      const int kp = kc * 8 + e;
      float val;
      if (kp < 7)       val = W1[kp * 64 + j];
      else if (kp < 14) val = W1[(kp - 7) * 64 + j];
      else if (kp == 14) val = b1[j];
      else { const float b = b1[j]; val = b - (float)(_Float16)b; }
      w1e[(kc * 64 + j) * 8 + e] = (_Float16)val;
    }
  }
  __syncthreads();

  float b2v[4];
  #pragma unroll
  for (int jt = 0; jt < 4; ++jt) b2v[jt] = b2[jt * 32 + col];
  f32x16 zf;
  #pragma unroll
  for (int e = 0; e < 16; ++e) zf[e] = 0.0f;

  // ---- chunk setup (CPW multiple of 64; N=4M is 64-aligned so pairs complete) ----
  const int gwave = blockIdx.x * 4 + w;
  const int start = gwave * CPW;
  if (start >= N) return;
  const int end = min(start + CPW, N);
  const int prevb = (start == 0) ? -1 : bidx[start - 1];
  const int nextb = (end >= N) ? -1 : bidx[end];
  int run_b = bidx[start];
  float run_s[4];
  #pragma unroll
  for (int jt = 0; jt < 4; ++jt) run_s[jt] = -3.0e38f;

  // W1 fragments hoisted (8 regs, loop-invariant)
  const half8 a1lo = *(const half8*)&w1e[(kh2 * 64 + col) * 8];
  const half8 a1hi = *(const half8*)&w1e[(kh2 * 64 + 32 + col) * 8];

  auto FLUSH = [&](int b, const float* m) {
    const bool interior = (b != prevb) && (b != nextb);
    if (lane < 32) {
      #pragma unroll
      for (int jt = 0; jt < 4; ++jt) {
        if (m[jt] > -2.9e38f) {
          const unsigned enc = f2mono(lrelu(m[jt] + b2v[jt]));
          unsigned* addr = &gf[b * 128 + jt * 32 + col];
          if (interior) *addr = enc; else atomicMax(addr, enc);
        }
      }
    }
  };

  // fp16 2-term decompose of the 7 inputs -> B1 fragment (bias slots folded)
  auto DECOMP = [&](float mu0, float mu1, float mu2, const f32x4& c4) -> half8 {
    float in[7];
    in[0] = mu0; in[1] = mu1; in[2] = mu2;
    in[3] = c4.x; in[4] = c4.y; in[5] = c4.z; in[6] = c4.w;
    const unsigned pA0 = pkrtz(in[0], in[1]);
    const unsigned pA1 = pkrtz(in[2], in[3]);
    const unsigned pA2 = pkrtz(in[4], in[5]);
    const half2v hA0 = __builtin_bit_cast(half2v, pA0);
    const half2v hA1 = __builtin_bit_cast(half2v, pA1);
    const half2v hA2 = __builtin_bit_cast(half2v, pA2);
    const float xl0 = in[0] - (float)hA0[0];
    const unsigned pA3 = pkrtz(in[6], xl0);
    const half2v hA3 = __builtin_bit_cast(half2v, pA3);
    const unsigned pB0 = pkrtz(in[1] - (float)hA0[1], in[2] - (float)hA1[0]);
    const unsigned pB1 = pkrtz(in[3] - (float)hA1[1], in[4] - (float)hA2[0]);
    const unsigned pB2 = pkrtz(in[5] - (float)hA2[1], in[6] - (float)hA3[0]);
    const unsigned pB3 = 0x3C003C00u;  // (1.0, 1.0) bias slots
    u32x4 bu;
    bu[0] = kh2 ? pB0 : pA0;
    bu[1] = kh2 ? pB1 : pA1;
    bu[2] = kh2 ? pB2 : pA2;
    bu[3] = kh2 ? pB3 : pA3;
    return ash8(bu);
  };

  // pack layer1 outputs + permlane-swap into 4 layer2 A-fragments
  auto MKAFRAG = [&](const f32x16& a0, const f32x16& a1, half8* Afr) {
    unsigned pk0[8], pk1[8];
    #pragma unroll
    for (int q = 0; q < 4; ++q) {
      pk0[2 * q]     = lrelu_pk(a0[4 * q],     a0[4 * q + 1]);
      pk0[2 * q + 1] = lrelu_pk(a0[4 * q + 2], a0[4 * q + 3]);
      pk1[2 * q]     = lrelu_pk(a1[4 * q],     a1[4 * q + 1]);
      pk1[2 * q + 1] = lrelu_pk(a1[4 * q + 2], a1[4 * q + 3]);
    }
    #pragma unroll
    for (int ks = 0; ks < 4; ++ks) {
      const unsigned* s = (ks < 2) ? pk0 : pk1;
      const int base = (ks & 1) * 4;
      unsigned x0 = s[base + 0], y0 = s[base + 2];
      unsigned x1 = s[base + 1], y1 = s[base + 3];
      plswap(x0, y0);
      plswap(x1, y1);
      u32x4 au;
      au[0] = x0; au[1] = x1; au[2] = y0; au[3] = y1;
      Afr[ks] = ash8(au);
    }
  };

  // layer2 (16 MFMAs, B-frags from LDS) + running segmented max for one tile
  auto L2SEG = [&](const half8* Afr, int bi) {
    f32x16 acc2[4];
    #pragma unroll
    for (int ks = 0; ks < 4; ++ks) {
      const int kcb = (2 * ks + kh2) * 128;
      #pragma unroll
      for (int jt = 0; jt < 4; ++jt) {
        const half8 B = *(const half8*)&w2f[(kcb + jt * 32 + col) * 8];
        acc2[jt] = __builtin_amdgcn_mfma_f32_32x32x16_f16(Afr[ks], B,
                                                          (ks == 0) ? zf : acc2[jt], 0, 0, 0);
      }
    }
    const int bA = __shfl(bi, 0);
    const int bB = __shfl(bi, 31);
    if (bA != run_b) {
      FLUSH(run_b, run_s);
      #pragma unroll
      for (int jt = 0; jt < 4; ++jt) run_s[jt] = -3.0e38f;
      run_b = bA;
    }
    if (bA == bB) {
      #pragma unroll
      for (int jt = 0; jt < 4; ++jt)
        run_s[jt] = fmaxf(run_s[jt], xhalf_max(max16(acc2[jt])));
    } else {
      int pbi[16];
      #pragma unroll
      for (int r = 0; r < 16; ++r) {
        const int rr = (r & 3) + ((r >> 2) << 3) + (kh2 << 2);
        pbi[r] = __shfl(bi, rr);
      }
      for (int b = bA; b <= bB; ++b) {
        float m[4];
        #pragma unroll
        for (int jt = 0; jt < 4; ++jt) {
          float mm = -3.0e38f;
          #pragma unroll
          for (int r = 0; r < 16; ++r)
            if (pbi[r] == b) mm = fmaxf(mm, acc2[jt][r]);
          mm = xhalf_max(mm);
          if (b == bA) mm = fmaxf(mm, run_s[jt]);
          m[jt] = mm;
        }
        if (b < bB) {
          FLUSH(b, m);
        } else {
          #pragma unroll
          for (int jt = 0; jt < 4; ++jt) run_s[jt] = m[jt];
        }
      }
      run_b = bB;
    }
  };

  // ---- input pipeline prologue (pair 0) ----
  int pA = min(start + col, N - 1);
  int pB = min(start + 32 + col, N - 1);
  int biA_n = bidx[pA], biB_n = bidx[pB];
  float muA_n[3] = {muons[pA * 3], muons[pA * 3 + 1], muons[pA * 3 + 2]};
  float muB_n[3] = {muons[pB * 3], muons[pB * 3 + 1], muons[pB * 3 + 2]};
  f32x4 c4A_n = *(const f32x4*)&cond[biA_n * 4];
  f32x4 c4B_n = *(const f32x4*)&cond[biB_n * 4];

  for (int pbase = start; pbase < end; pbase += 64) {
    // consume prefetched pair
    const int biA = biA_n, biB = biB_n;
    const float mA0 = muA_n[0], mA1 = muA_n[1], mA2 = muA_n[2];
    const float mB0 = muB_n[0], mB1 = muB_n[1], mB2 = muB_n[2];
    const f32x4 c4A = c4A_n, c4B = c4B_n;

    // issue next pair's independent loads NOW
    const int pnA = min(pbase + 64 + col, N - 1);
    const int pnB = min(pbase + 96 + col, N - 1);
    biA_n = bidx[pnA]; biB_n = bidx[pnB];
    muA_n[0] = muons[pnA * 3]; muA_n[1] = muons[pnA * 3 + 1]; muA_n[2] = muons[pnA * 3 + 2];
    muB_n[0] = muons[pnB * 3]; muB_n[1] = muons[pnB * 3 + 1]; muB_n[2] = muons[pnB * 3 + 2];

    // ---- decompose + layer1 for BOTH tiles (independent MFMA chains) ----
    const half8 bfrA = DECOMP(mA0, mA1, mA2, c4A);
    const half8 bfrB = DECOMP(mB0, mB1, mB2, c4B);
    const f32x16 aA0 = __builtin_amdgcn_mfma_f32_32x32x16_f16(a1lo, bfrA, zf, 0, 0, 0);
    const f32x16 aA1 = __builtin_amdgcn_mfma_f32_32x32x16_f16(a1hi, bfrA, zf, 0, 0, 0);
    const f32x16 aB0 = __builtin_amdgcn_mfma_f32_32x32x16_f16(a1lo, bfrB, zf, 0, 0, 0);
    const f32x16 aB1 = __builtin_amdgcn_mfma_f32_32x32x16_f16(a1hi, bfrB, zf, 0, 0, 0);

    // dependent cond gathers for next pair (bi*_n arrived by now)
    c4A_n = *(const f32x4*)&cond[biA_n * 4];
    c4B_n = *(const f32x4*)&cond[biB_n * 4];

    // ---- pack + swap both tiles ----
    half8 AfrA[4], AfrB[4];
    MKAFRAG(aA0, aA1, AfrA);
    MKAFRAG(aB0, aB1, AfrB);

    // ---- layer2 + seg-max, tile A then tile B (acc regs reused) ----
    L2SEG(AfrA, biA);
    L2SEG(AfrB, biB);
  }
  FLUSH(run_b, run_s);
}

// ---------------- decision MLP: [B,132] @ W3 -> lrelu -> @ W4 + b4 ----------------
// Grid MUST stay ~1024: at 67.5KB LDS only 2 blocks/CU fit; 256 blocks leaves
// 2 waves/CU => latency-starved (R7: ~60us vs ~25us). Do not shrink the grid.
__global__ __launch_bounds__(128) void sc_final(
    const unsigned* __restrict__ gf, const float* __restrict__ cond,
    const float* __restrict__ W3, const float* __restrict__ b3,
    const float* __restrict__ W4, const float* __restrict__ b4,
    float* __restrict__ out, int B) {
  __shared__ __align__(16) float w3t[128 * 132];  // [j][k]
  __shared__ float b3s[128], w4s[128];
  __shared__ __align__(16) float din[8 * 132];
  __shared__ float wred[16];
  const int t = threadIdx.x;
  for (int k = 0; k < 132; ++k) w3t[t * 132 + k] = W3[k * 128 + t];
  b3s[t] = b3[t];
  w4s[t] = W4[t];
  __syncthreads();

  const int nocts = (B + 7) >> 3;
  for (int oc = blockIdx.x; oc < nocts; oc += gridDim.x) {
    const int rbase = oc << 3;
    #pragma unroll
    for (int r = 0; r < 8; ++r) {
      const int row = rbase + r;
      if (row < B) {
        din[r * 132 + t] = mono2f(gf[row * 128 + t]);
        if (t < 4) din[r * 132 + 128 + t] = cond[row * 4 + t];
      }
    }
    __syncthreads();
    float a8[8];
    #pragma unroll
    for (int r = 0; r < 8; ++r) a8[r] = b3s[t];
    for (int kg = 0; kg < 33; ++kg) {
      const f32x4 wv = *(const f32x4*)&w3t[t * 132 + kg * 4];
      #pragma unroll
      for (int r = 0; r < 8; ++r) {
        const f32x4 dv = *(const f32x4*)&din[r * 132 + kg * 4];
        a8[r] += wv[0] * dv[0] + wv[1] * dv[1] + wv[2] * dv[2] + wv[3] * dv[3];
      }
    }
    const float w4v = w4s[t];
    #pragma unroll
    for (int r = 0; r < 8; ++r) a8[r] = lrelu(a8[r]) * w4v;
    const int lane = t & 63;
    const int wv_ = t >> 6;
    #pragma unroll
    for (int r = 0; r < 8; ++r) {
      float s = a8[r];
      s += __shfl_xor(s, 1);  s += __shfl_xor(s, 2);
      s += __shfl_xor(s, 4);  s += __shfl_xor(s, 8);
      s += __shfl_xor(s, 16); s += __shfl_xor(s, 32);
      if (lane == 0) wred[wv_ * 8 + r] = s;
    }
    __syncthreads();
    if (t < 8) {
      const int row = rbase + t;
      if (row < B) out[row] = wred[t] + wred[8 + t] + b4[0];
    }
    __syncthreads();
  }
}

extern "C" void kernel_launch(void* const* d_in, const int* in_sizes, int n_in,
                              void* d_out, int out_size, void* d_ws, size_t ws_size,
                              hipStream_t stream) {
  const float* muons = (const float*)d_in[0];
  const int* bidx = (const int*)d_in[1];
  const float* cond = (const float*)d_in[2];
  const float* W1 = (const float*)d_in[4];
  const float* b1 = (const float*)d_in[5];
  const float* W2 = (const float*)d_in[6];
  const float* b2 = (const float*)d_in[7];
  const float* W3 = (const float*)d_in[8];
  const float* b3 = (const float*)d_in[9];
  const float* W4 = (const float*)d_in[10];
  const float* b4 = (const float*)d_in[11];
  float* out = (float*)d_out;
  const int N = in_sizes[1];
  const int B = out_size;
  unsigned* gf = (unsigned*)d_ws;  // B*128 mono-encoded uints (8 MB)

  const int total4 = (B * 128) / 4;
  sc_init<<<(total4 + 255) / 256, 256, 0, stream>>>(gf, total4);

  const int nblocks = 2048;
  const int nwaves = nblocks * 4;
  const int cpw = (((N + nwaves - 1) / nwaves) + 63) & ~63;  // points per wave, ×64
  sc_main<<<nblocks, 256, 0, stream>>>(muons, bidx, cond, W1, b1, W2, b2, gf, N, cpw);
  sc_final<<<1024, 128, 0, stream>>>(gf, cond, W3, b3, W4, b4, out, B);
  (void)n_in; (void)ws_size;
}

// Round 11
// 124.242 us; speedup vs baseline: 1.5711x; 1.2182x over previous
//
#include <hip/hip_runtime.h>

typedef float f32x4 __attribute__((ext_vector_type(4)));
typedef float f32x16 __attribute__((ext_vector_type(16)));
typedef _Float16 half8 __attribute__((ext_vector_type(8)));
typedef _Float16 half2v __attribute__((ext_vector_type(2)));
typedef unsigned u32x4 __attribute__((ext_vector_type(4)));

__device__ __forceinline__ unsigned f2mono(float f) {
  unsigned u = __float_as_uint(f);
  return (u & 0x80000000u) ? ~u : (u | 0x80000000u);
}
__device__ __forceinline__ float mono2f(unsigned u) {
  return (u & 0x80000000u) ? __uint_as_float(u & 0x7fffffffu) : __uint_as_float(~u);
}
__device__ __forceinline__ float lrelu(float x) { return fmaxf(x, 0.2f * x); }
__device__ __forceinline__ unsigned pkrtz(float a, float b) {
  return __builtin_bit_cast(unsigned, __builtin_amdgcn_cvt_pkrtz(a, b));
}
// packed lrelu on a cvt_pkrtz pair: v_pk_mul_f16 + v_pk_max_f16
__device__ __forceinline__ unsigned lrelu_pk(float a, float b) {
  const half2v v = __builtin_bit_cast(half2v, pkrtz(a, b));
  const half2v s = v * (half2v){(_Float16)0.2f, (_Float16)0.2f};
  return __builtin_bit_cast(unsigned, __builtin_elementwise_max(v, s));
}
__device__ __forceinline__ half8 ash8(u32x4 u) { return __builtin_bit_cast(half8, u); }
// 16-value max shaped for v_max3_f32 fusion
__device__ __forceinline__ float max16(const f32x16& a) {
  const float m1 = fmaxf(fmaxf(a[0], a[1]), a[2]);
  const float m2 = fmaxf(fmaxf(a[3], a[4]), a[5]);
  const float m3 = fmaxf(fmaxf(a[6], a[7]), a[8]);
  const float m4 = fmaxf(fmaxf(a[9], a[10]), a[11]);
  const float m5 = fmaxf(fmaxf(a[12], a[13]), a[14]);
  return fmaxf(fmaxf(fmaxf(m1, m2), m3), fmaxf(fmaxf(m4, m5), a[15]));
}
// v_permlane32_swap_b32: x' = {x.lo, y.lo}, y' = {x.hi, y.hi} (lane halves)
__device__ __forceinline__ void plswap(unsigned& x, unsigned& y) {
  asm volatile("v_permlane32_swap_b32 %0, %1" : "+v"(x), "+v"(y));
}
// cross-half max in pure VALU: lane i gets fmax(m[i&31], m[(i&31)+32])
// REQUIRES full-wave-active (uniform) call site.
__device__ __forceinline__ float xhalf_max(float m) {
  unsigned a = __float_as_uint(m), b = a;
  plswap(a, b);
  return fmaxf(__uint_as_float(a), __uint_as_float(b));
}

// ---------------- init: global_feats = mono(-1e9) ----------------
__global__ void sc_init(unsigned* __restrict__ gf, int total4) {
  int i = blockIdx.x * blockDim.x + threadIdx.x;
  if (i < total4) {
    unsigned m = f2mono(-1.0e9f);
    ((uint4*)gf)[i] = make_uint4(m, m, m, m);
  }
}

// ---- fused: gather + L1(fp16 x-split MFMA) + L2(fp16 MFMA) + running seg-max ----
// Two 32-point tiles stage-interleaved per iteration (ILP at the 2-waves/SIMD
// occupancy floor). run_s holds PER-HALF partial maxes; FLUSH does the
// cross-half merge (permlane) before its lane<32 guard — all FLUSH call sites
// are wave-uniform. Boundary tiles use a ballot-derived split (sorted index)
// instead of 16 serial shfls; >=3-batch tiles fall back to the general loop.
// __launch_bounds__(256,2): pins allocator at no-spill point (R4/R6/R8).
// Greedy defaults pick VGPR 64 => 0.9-2.3 GB scratch (R3/R5). Keep.
__global__ __launch_bounds__(256, 2) void sc_main(
    const float* __restrict__ muons, const int* __restrict__ bidx,
    const float* __restrict__ cond, const float* __restrict__ W1,
    const float* __restrict__ b1, const float* __restrict__ W2,
    const float* __restrict__ b2, unsigned* __restrict__ gf, int N, int CPW) {
  __shared__ __align__(16) _Float16 w2f[8192];  // [kc=8][j2=128][e=8] blocked
  __shared__ __align__(16) _Float16 w1e[1024];  // [kc=2][j=64][e=8]: k'=0-6 W1h,7-13 W1h(xl),14 b1h,15 b1l

  const int t = threadIdx.x;
  const int w = t >> 6;
  const int lane = t & 63;
  const int col = lane & 31;
  const int kh2 = lane >> 5;

  // ---- one-time weight staging ----
  {
    const int j = t & 127, kh = t >> 7;
    for (int kk = 0; kk < 32; ++kk) {
      const int k = kh * 32 + kk;
      w2f[((k >> 3) * 128 + j) * 8 + (k & 7)] = (_Float16)W2[k * 128 + j];
    }
  }
  if (t < 128) {
    const int j = t & 63, kc = t >> 6;
    for (int e = 0; e < 8; ++e) {
      const int kp = kc * 8 + e;
      float val;
      if (kp < 7)       val = W1[kp * 64 + j];
      else if (kp < 14) val = W1[(kp - 7) * 64 + j];
      else if (kp == 14) val = b1[j];
      else { const float b = b1[j]; val = b - (float)(_Float16)b; }
      w1e[(kc * 64 + j) * 8 + e] = (_Float16)val;
    }
  }
  __syncthreads();

  float b2v[4];
  #pragma unroll
  for (int jt = 0; jt < 4; ++jt) b2v[jt] = b2[jt * 32 + col];
  f32x16 zf;
  #pragma unroll
  for (int e = 0; e < 16; ++e) zf[e] = 0.0f;

  // ---- chunk setup (CPW multiple of 64) ----
  const int gwave = blockIdx.x * 4 + w;
  const int start = gwave * CPW;
  if (start >= N) return;
  const int end = min(start + CPW, N);
  const int prevb = (start == 0) ? -1 : bidx[start - 1];
  const int nextb = (end >= N) ? -1 : bidx[end];
  int run_b = bidx[start];
  float run_s[4];
  #pragma unroll
  for (int jt = 0; jt < 4; ++jt) run_s[jt] = -3.0e38f;

  // W1 fragments hoisted (8 regs, loop-invariant)
  const half8 a1lo = *(const half8*)&w1e[(kh2 * 64 + col) * 8];
  const half8 a1hi = *(const half8*)&w1e[(kh2 * 64 + 32 + col) * 8];

  // m[] holds per-half partials; merge across halves HERE (uniform call sites)
  auto FLUSH = [&](int b, const float* m) {
    const bool interior = (b != prevb) && (b != nextb);
    float mm[4];
    #pragma unroll
    for (int jt = 0; jt < 4; ++jt) mm[jt] = xhalf_max(m[jt]);
    if (lane < 32) {
      #pragma unroll
      for (int jt = 0; jt < 4; ++jt) {
        if (mm[jt] > -2.9e38f) {
          const unsigned enc = f2mono(lrelu(mm[jt] + b2v[jt]));
          unsigned* addr = &gf[b * 128 + jt * 32 + col];
          if (interior) *addr = enc; else atomicMax(addr, enc);
        }
      }
    }
  };

  // fp16 2-term decompose of the 7 inputs -> B1 fragment (bias slots folded)
  auto DECOMP = [&](float mu0, float mu1, float mu2, const f32x4& c4) -> half8 {
    float in[7];
    in[0] = mu0; in[1] = mu1; in[2] = mu2;
    in[3] = c4.x; in[4] = c4.y; in[5] = c4.z; in[6] = c4.w;
    const unsigned pA0 = pkrtz(in[0], in[1]);
    const unsigned pA1 = pkrtz(in[2], in[3]);
    const unsigned pA2 = pkrtz(in[4], in[5]);
    const half2v hA0 = __builtin_bit_cast(half2v, pA0);
    const half2v hA1 = __builtin_bit_cast(half2v, pA1);
    const half2v hA2 = __builtin_bit_cast(half2v, pA2);
    const float xl0 = in[0] - (float)hA0[0];
    const unsigned pA3 = pkrtz(in[6], xl0);
    const half2v hA3 = __builtin_bit_cast(half2v, pA3);
    const unsigned pB0 = pkrtz(in[1] - (float)hA0[1], in[2] - (float)hA1[0]);
    const unsigned pB1 = pkrtz(in[3] - (float)hA1[1], in[4] - (float)hA2[0]);
    const unsigned pB2 = pkrtz(in[5] - (float)hA2[1], in[6] - (float)hA3[0]);
    const unsigned pB3 = 0x3C003C00u;  // (1.0, 1.0) bias slots
    u32x4 bu;
    bu[0] = kh2 ? pB0 : pA0;
    bu[1] = kh2 ? pB1 : pA1;
    bu[2] = kh2 ? pB2 : pA2;
    bu[3] = kh2 ? pB3 : pA3;
    return ash8(bu);
  };

  // pack layer1 outputs + permlane-swap into 4 layer2 A-fragments
  auto MKAFRAG = [&](const f32x16& a0, const f32x16& a1, half8* Afr) {
    unsigned pk0[8], pk1[8];
    #pragma unroll
    for (int q = 0; q < 4; ++q) {
      pk0[2 * q]     = lrelu_pk(a0[4 * q],     a0[4 * q + 1]);
      pk0[2 * q + 1] = lrelu_pk(a0[4 * q + 2], a0[4 * q + 3]);
      pk1[2 * q]     = lrelu_pk(a1[4 * q],     a1[4 * q + 1]);
      pk1[2 * q + 1] = lrelu_pk(a1[4 * q + 2], a1[4 * q + 3]);
    }
    #pragma unroll
    for (int ks = 0; ks < 4; ++ks) {
      const unsigned* s = (ks < 2) ? pk0 : pk1;
      const int base = (ks & 1) * 4;
      unsigned x0 = s[base + 0], y0 = s[base + 2];
      unsigned x1 = s[base + 1], y1 = s[base + 3];
      plswap(x0, y0);
      plswap(x1, y1);
      u32x4 au;
      au[0] = x0; au[1] = x1; au[2] = y0; au[3] = y1;
      Afr[ks] = ash8(au);
    }
  };

  // layer2 (16 MFMAs, B-frags from LDS) + running segmented max for one tile
  auto L2SEG = [&](const half8* Afr, int bi) {
    f32x16 acc2[4];
    #pragma unroll
    for (int ks = 0; ks < 4; ++ks) {
      const int kcb = (2 * ks + kh2) * 128;
      #pragma unroll
      for (int jt = 0; jt < 4; ++jt) {
        const half8 B = *(const half8*)&w2f[(kcb + jt * 32 + col) * 8];
        acc2[jt] = __builtin_amdgcn_mfma_f32_32x32x16_f16(Afr[ks], B,
                                                          (ks == 0) ? zf : acc2[jt], 0, 0, 0);
      }
    }
    const int bA = __shfl(bi, 0);
    const int bB = __shfl(bi, 31);
    if (bA != run_b) {
      FLUSH(run_b, run_s);
      #pragma unroll
      for (int jt = 0; jt < 4; ++jt) run_s[jt] = -3.0e38f;
      run_b = bA;
    }
    if (bA == bB) {
      #pragma unroll
      for (int jt = 0; jt < 4; ++jt)
        run_s[jt] = fmaxf(run_s[jt], max16(acc2[jt]));
    } else {
      // boundary tile: sorted => lanes with bi==bA are exactly 0..split-1
      const unsigned long long ball = __ballot(bi == bA);
      const int split = (int)__popcll(ball & 0xffffffffULL);
      const int bS = __shfl(bi, split);
      if (bS == bB) {
        // exactly two batches (common case): uniform-split masked maxes
        float mA[4], mB[4];
        #pragma unroll
        for (int jt = 0; jt < 4; ++jt) { mA[jt] = -3.0e38f; mB[jt] = -3.0e38f; }
        #pragma unroll
        for (int r = 0; r < 16; ++r) {
          const int rr = (r & 3) + ((r >> 2) << 3) + (kh2 << 2);
          const bool inA = rr < split;
          #pragma unroll
          for (int jt = 0; jt < 4; ++jt) {
            const float v = acc2[jt][r];
            mA[jt] = fmaxf(mA[jt], inA ? v : -3.0e38f);
            mB[jt] = fmaxf(mB[jt], inA ? -3.0e38f : v);
          }
        }
        #pragma unroll
        for (int jt = 0; jt < 4; ++jt) mA[jt] = fmaxf(mA[jt], run_s[jt]);
        FLUSH(bA, mA);
        #pragma unroll
        for (int jt = 0; jt < 4; ++jt) run_s[jt] = mB[jt];
        run_b = bB;
      } else {
        // >=3 batches in one 32-tile (rare): general loop
        int pbi[16];
        #pragma unroll
        for (int r = 0; r < 16; ++r) {
          const int rr = (r & 3) + ((r >> 2) << 3) + (kh2 << 2);
          pbi[r] = __shfl(bi, rr);
        }
        for (int b = bA; b <= bB; ++b) {
          float m[4];
          #pragma unroll
          for (int jt = 0; jt < 4; ++jt) {
            float mm = -3.0e38f;
            #pragma unroll
            for (int r = 0; r < 16; ++r)
              if (pbi[r] == b) mm = fmaxf(mm, acc2[jt][r]);
            if (b == bA) mm = fmaxf(mm, run_s[jt]);
            m[jt] = mm;
          }
          if (b < bB) {
            FLUSH(b, m);
          } else {
            #pragma unroll
            for (int jt = 0; jt < 4; ++jt) run_s[jt] = m[jt];
          }
        }
        run_b = bB;
      }
    }
  };

  // ---- input pipeline prologue (pair 0) ----
  int pA = min(start + col, N - 1);
  int pB = min(start + 32 + col, N - 1);
  int biA_n = bidx[pA], biB_n = bidx[pB];
  float muA_n[3] = {muons[pA * 3], muons[pA * 3 + 1], muons[pA * 3 + 2]};
  float muB_n[3] = {muons[pB * 3], muons[pB * 3 + 1], muons[pB * 3 + 2]};
  f32x4 c4A_n = *(const f32x4*)&cond[biA_n * 4];
  f32x4 c4B_n = *(const f32x4*)&cond[biB_n * 4];

  for (int pbase = start; pbase < end; pbase += 64) {
    const int biA = biA_n, biB = biB_n;
    const float mA0 = muA_n[0], mA1 = muA_n[1], mA2 = muA_n[2];
    const float mB0 = muB_n[0], mB1 = muB_n[1], mB2 = muB_n[2];
    const f32x4 c4A = c4A_n, c4B = c4B_n;

    // issue next pair's independent loads NOW
    const int pnA = min(pbase + 64 + col, N - 1);
    const int pnB = min(pbase + 96 + col, N - 1);
    biA_n = bidx[pnA]; biB_n = bidx[pnB];
    muA_n[0] = muons[pnA * 3]; muA_n[1] = muons[pnA * 3 + 1]; muA_n[2] = muons[pnA * 3 + 2];
    muB_n[0] = muons[pnB * 3]; muB_n[1] = muons[pnB * 3 + 1]; muB_n[2] = muons[pnB * 3 + 2];

    // ---- decompose + layer1 for BOTH tiles (independent MFMA chains) ----
    const half8 bfrA = DECOMP(mA0, mA1, mA2, c4A);
    const half8 bfrB = DECOMP(mB0, mB1, mB2, c4B);
    const f32x16 aA0 = __builtin_amdgcn_mfma_f32_32x32x16_f16(a1lo, bfrA, zf, 0, 0, 0);
    const f32x16 aA1 = __builtin_amdgcn_mfma_f32_32x32x16_f16(a1hi, bfrA, zf, 0, 0, 0);
    const f32x16 aB0 = __builtin_amdgcn_mfma_f32_32x32x16_f16(a1lo, bfrB, zf, 0, 0, 0);
    const f32x16 aB1 = __builtin_amdgcn_mfma_f32_32x32x16_f16(a1hi, bfrB, zf, 0, 0, 0);

    // dependent cond gathers for next pair (bi*_n arrived by now)
    c4A_n = *(const f32x4*)&cond[biA_n * 4];
    c4B_n = *(const f32x4*)&cond[biB_n * 4];

    // ---- pack + swap both tiles ----
    half8 AfrA[4], AfrB[4];
    MKAFRAG(aA0, aA1, AfrA);
    MKAFRAG(aB0, aB1, AfrB);

    // ---- layer2 + seg-max, tile A then tile B (acc regs reused) ----
    L2SEG(AfrA, biA);
    L2SEG(AfrB, biB);
  }
  FLUSH(run_b, run_s);
}

// ---- decision MLP via 3-term split-fp16 MFMA: [B,132+bias] @ W3 -> lrelu -> .W4 + b4 ----
// Per wave: 32 batch rows. A = W3 hi/lo frags in LDS (b3 folded at k-slot 132,
// K padded to 144 = 9 chunks); B = din from gf (mono decode -> hi/lo fp16).
// 3-term MFMA keeps decision layer fp32-equivalent. Epilogue: lrelu, per-lane
// W4 dot (j static per reg), permlane cross-half add, coalesced store.
// __launch_bounds__(256,2): live state ~170 regs; default allocator would spill.
__global__ __launch_bounds__(256, 2) void sc_final(
    const unsigned* __restrict__ gf, const float* __restrict__ cond,
    const float* __restrict__ W3, const float* __restrict__ b3,
    const float* __restrict__ W4, const float* __restrict__ b4,
    float* __restrict__ out, int B) {
  __shared__ __align__(16) _Float16 w3h[18432];  // [h=k>>3 (18)][j (128)][e=k&7 (8)]
  __shared__ __align__(16) _Float16 w3l[18432];
  __shared__ float w4s[128];
  const int t = threadIdx.x;
  const int w = t >> 6, lane = t & 63, col = lane & 31, kh2 = lane >> 5;

  for (int i = t; i < 144 * 128; i += 256) {
    const int k = i >> 7, j = i & 127;
    float v = 0.0f;
    if (k < 132) v = W3[k * 128 + j];
    else if (k == 132) v = b3[j];
    const _Float16 h = (_Float16)v;
    const int a = ((k >> 3) * 128 + j) * 8 + (k & 7);
    w3h[a] = h;
    w3l[a] = (_Float16)(v - (float)h);
  }
  if (t < 128) w4s[t] = W4[t];
  __syncthreads();

  const int tile = blockIdx.x * 4 + w;
  const int row = tile * 32 + col;
  const int rc = min(row, B - 1);

  // all gf data for this row's k-half: 16 x dwordx4, issued upfront
  uint4 g[16];
  #pragma unroll
  for (int kc = 0; kc < 8; ++kc) {
    const int base = rc * 128 + kc * 16 + kh2 * 8;
    g[2 * kc]     = *(const uint4*)&gf[base];
    g[2 * kc + 1] = *(const uint4*)&gf[base + 4];
  }
  const f32x4 c4 = *(const f32x4*)&cond[rc * 4];

  f32x16 zf;
  #pragma unroll
  for (int e = 0; e < 16; ++e) zf[e] = 0.0f;
  f32x16 acc[4];

  #pragma unroll
  for (int kc = 0; kc < 9; ++kc) {
    float v[8];
    if (kc < 8) {
      const uint4 ga = g[2 * kc], gb = g[2 * kc + 1];
      v[0] = mono2f(ga.x); v[1] = mono2f(ga.y); v[2] = mono2f(ga.z); v[3] = mono2f(ga.w);
      v[4] = mono2f(gb.x); v[5] = mono2f(gb.y); v[6] = mono2f(gb.z); v[7] = mono2f(gb.w);
    } else if (kh2 == 0) {
      v[0] = c4.x; v[1] = c4.y; v[2] = c4.z; v[3] = c4.w;
      v[4] = 1.0f; v[5] = 0.0f; v[6] = 0.0f; v[7] = 0.0f;  // k=132 -> b3 slot
    } else {
      #pragma unroll
      for (int e = 0; e < 8; ++e) v[e] = 0.0f;
    }
    u32x4 bh, bl;
    #pragma unroll
    for (int q = 0; q < 4; ++q) {
      const unsigned ph = pkrtz(v[2 * q], v[2 * q + 1]);
      const half2v hh = __builtin_bit_cast(half2v, ph);
      bh[q] = ph;
      bl[q] = pkrtz(v[2 * q] - (float)hh[0], v[2 * q + 1] - (float)hh[1]);
    }
    const half8 Bh = ash8(bh), Bl = ash8(bl);
    #pragma unroll
    for (int jt = 0; jt < 4; ++jt) {
      const int a = ((kc * 2 + kh2) * 128 + jt * 32 + col) * 8;
      const half8 Ah = *(const half8*)&w3h[a];
      const half8 Al = *(const half8*)&w3l[a];
      f32x16 c = (kc == 0) ? zf : acc[jt];
      c = __builtin_amdgcn_mfma_f32_32x32x16_f16(Ah, Bh, c, 0, 0, 0);
      c = __builtin_amdgcn_mfma_f32_32x32x16_f16(Ah, Bl, c, 0, 0, 0);
      c = __builtin_amdgcn_mfma_f32_32x32x16_f16(Al, Bh, c, 0, 0, 0);
      acc[jt] = c;
    }
  }

  // h3 -> lrelu -> dot W4 over this lane's kh2 j-half
  float partial = 0.0f;
  #pragma unroll
  for (int jt = 0; jt < 4; ++jt)
    #pragma unroll
    for (int r = 0; r < 16; ++r) {
      const int j = jt * 32 + (r & 3) + ((r >> 2) << 3) + (kh2 << 2);
      partial += lrelu(acc[jt][r]) * w4s[j];
    }
  unsigned pa = __float_as_uint(partial), pb = pa;
  plswap(pa, pb);
  const float tot = __uint_as_float(pa) + __uint_as_float(pb);
  if (lane < 32 && row < B) out[row] = tot + b4[0];
}

extern "C" void kernel_launch(void* const* d_in, const int* in_sizes, int n_in,
                              void* d_out, int out_size, void* d_ws, size_t ws_size,
                              hipStream_t stream) {
  const float* muons = (const float*)d_in[0];
  const int* bidx = (const int*)d_in[1];
  const float* cond = (const float*)d_in[2];
  const float* W1 = (const float*)d_in[4];
  const float* b1 = (const float*)d_in[5];
  const float* W2 = (const float*)d_in[6];
  const float* b2 = (const float*)d_in[7];
  const float* W3 = (const float*)d_in[8];
  const float* b3 = (const float*)d_in[9];
  const float* W4 = (const float*)d_in[10];
  const float* b4 = (const float*)d_in[11];
  float* out = (float*)d_out;
  const int N = in_sizes[1];
  const int B = out_size;
  unsigned* gf = (unsigned*)d_ws;  // B*128 mono-encoded uints (8 MB)

  const int total4 = (B * 128) / 4;
  sc_init<<<(total4 + 255) / 256, 256, 0, stream>>>(gf, total4);

  const int nblocks = 2048;
  const int nwaves = nblocks * 4;
  const int cpw = (((N + nwaves - 1) / nwaves) + 63) & ~63;  // points per wave, ×64
  sc_main<<<nblocks, 256, 0, stream>>>(muons, bidx, cond, W1, b1, W2, b2, gf, N, cpw);

  const int ftiles = (B + 31) / 32;
  const int fblocks = (ftiles + 3) / 4;
  sc_final<<<fblocks, 256, 0, stream>>>(gf, cond, W3, b3, W4, b4, out, B);
  (void)n_in; (void)ws_size;
}

// Round 12
// 121.590 us; speedup vs baseline: 1.6053x; 1.0218x over previous
//
#include <hip/hip_runtime.h>

typedef float f32x4 __attribute__((ext_vector_type(4)));
typedef float f32x16 __attribute__((ext_vector_type(16)));
typedef _Float16 half8 __attribute__((ext_vector_type(8)));
typedef _Float16 half2v __attribute__((ext_vector_type(2)));
typedef unsigned u32x4 __attribute__((ext_vector_type(4)));

__device__ __forceinline__ unsigned f2mono(float f) {
  unsigned u = __float_as_uint(f);
  return (u & 0x80000000u) ? ~u : (u | 0x80000000u);
}
__device__ __forceinline__ float mono2f(unsigned u) {
  return (u & 0x80000000u) ? __uint_as_float(u & 0x7fffffffu) : __uint_as_float(~u);
}
__device__ __forceinline__ float lrelu(float x) { return fmaxf(x, 0.2f * x); }
__device__ __forceinline__ unsigned pkrtz(float a, float b) {
  return __builtin_bit_cast(unsigned, __builtin_amdgcn_cvt_pkrtz(a, b));
}
// packed lrelu on a cvt_pkrtz pair: v_pk_mul_f16 + v_pk_max_f16
__device__ __forceinline__ unsigned lrelu_pk(float a, float b) {
  const half2v v = __builtin_bit_cast(half2v, pkrtz(a, b));
  const half2v s = v * (half2v){(_Float16)0.2f, (_Float16)0.2f};
  return __builtin_bit_cast(unsigned, __builtin_elementwise_max(v, s));
}
__device__ __forceinline__ half8 ash8(u32x4 u) { return __builtin_bit_cast(half8, u); }
// 16-value max shaped for v_max3_f32 fusion
__device__ __forceinline__ float max16(const f32x16& a) {
  const float m1 = fmaxf(fmaxf(a[0], a[1]), a[2]);
  const float m2 = fmaxf(fmaxf(a[3], a[4]), a[5]);
  const float m3 = fmaxf(fmaxf(a[6], a[7]), a[8]);
  const float m4 = fmaxf(fmaxf(a[9], a[10]), a[11]);
  const float m5 = fmaxf(fmaxf(a[12], a[13]), a[14]);
  return fmaxf(fmaxf(fmaxf(m1, m2), m3), fmaxf(fmaxf(m4, m5), a[15]));
}
// v_permlane32_swap_b32: x' = {x.lo, y.lo}, y' = {x.hi, y.hi} (lane halves)
__device__ __forceinline__ void plswap(unsigned& x, unsigned& y) {
  asm volatile("v_permlane32_swap_b32 %0, %1" : "+v"(x), "+v"(y));
}
// cross-half max in pure VALU: lane i gets fmax(m[i&31], m[(i&31)+32])
// REQUIRES full-wave-active (uniform) call site.
__device__ __forceinline__ float xhalf_max(float m) {
  unsigned a = __float_as_uint(m), b = a;
  plswap(a, b);
  return fmaxf(__uint_as_float(a), __uint_as_float(b));
}

// ---------------- init: global_feats = mono(-1e9) ----------------
__global__ void sc_init(unsigned* __restrict__ gf, int total4) {
  int i = blockIdx.x * blockDim.x + threadIdx.x;
  if (i < total4) {
    unsigned m = f2mono(-1.0e9f);
    ((uint4*)gf)[i] = make_uint4(m, m, m, m);
  }
}

// ---- fused: gather + L1(fp16 x-split MFMA) + L2(fp16 MFMA) + running seg-max ----
// Two 32-point tiles stage-interleaved per iteration; L2+segmax runs in two
// j-half passes (acc AGPR 64->32) so 3 waves/SIMD fit under launch_bounds
// (256,3) [cap ~170 regs; live ~124]. run_s holds PER-HALF partial maxes;
// FLUSH2 merges across halves (permlane, wave-uniform call sites).
// R3 lesson: a cap BELOW live state => 0.9-2.3 GB scratch. Tripwire: FETCH_SIZE.
__global__ __launch_bounds__(256, 3) void sc_main(
    const float* __restrict__ muons, const int* __restrict__ bidx,
    const float* __restrict__ cond, const float* __restrict__ W1,
    const float* __restrict__ b1, const float* __restrict__ W2,
    const float* __restrict__ b2, unsigned* __restrict__ gf, int N, int CPW) {
  __shared__ __align__(16) _Float16 w2f[8192];  // [kc=8][j2=128][e=8] blocked
  __shared__ __align__(16) _Float16 w1e[1024];  // [kc=2][j=64][e=8]: k'=0-6 W1h,7-13 W1h(xl),14 b1h,15 b1l

  const int t = threadIdx.x;
  const int w = t >> 6;
  const int lane = t & 63;
  const int col = lane & 31;
  const int kh2 = lane >> 5;

  // ---- one-time weight staging ----
  {
    const int j = t & 127, kh = t >> 7;
    for (int kk = 0; kk < 32; ++kk) {
      const int k = kh * 32 + kk;
      w2f[((k >> 3) * 128 + j) * 8 + (k & 7)] = (_Float16)W2[k * 128 + j];
    }
  }
  if (t < 128) {
    const int j = t & 63, kc = t >> 6;
    for (int e = 0; e < 8; ++e) {
      const int kp = kc * 8 + e;
      float val;
      if (kp < 7)       val = W1[kp * 64 + j];
      else if (kp < 14) val = W1[(kp - 7) * 64 + j];
      else if (kp == 14) val = b1[j];
      else { const float b = b1[j]; val = b - (float)(_Float16)b; }
      w1e[(kc * 64 + j) * 8 + e] = (_Float16)val;
    }
  }
  __syncthreads();

  float b2v[4];
  #pragma unroll
  for (int jt = 0; jt < 4; ++jt) b2v[jt] = b2[jt * 32 + col];
  f32x16 zf;
  #pragma unroll
  for (int e = 0; e < 16; ++e) zf[e] = 0.0f;

  // ---- chunk setup (CPW multiple of 64) ----
  const int gwave = blockIdx.x * 4 + w;
  const int start = gwave * CPW;
  if (start >= N) return;
  const int end = min(start + CPW, N);
  const int prevb = (start == 0) ? -1 : bidx[start - 1];
  const int nextb = (end >= N) ? -1 : bidx[end];
  int run_b = bidx[start];
  float run_s[4];
  #pragma unroll
  for (int jt = 0; jt < 4; ++jt) run_s[jt] = -3.0e38f;

  // W1 fragments hoisted (8 regs, loop-invariant)
  const half8 a1lo = *(const half8*)&w1e[(kh2 * 64 + col) * 8];
  const half8 a1hi = *(const half8*)&w1e[(kh2 * 64 + 32 + col) * 8];

  // flush 2 feature-groups (jtb, jtb+1); m holds per-half partials, merged here.
  // All call sites wave-uniform (required by permlane).
  auto FLUSH2 = [&](int b, int jtb, float m0, float m1) {
    const bool interior = (b != prevb) && (b != nextb);
    const float g0 = xhalf_max(m0);
    const float g1 = xhalf_max(m1);
    if (lane < 32) {
      if (g0 > -2.9e38f) {
        const unsigned enc = f2mono(lrelu(g0 + b2v[jtb]));
        unsigned* addr = &gf[b * 128 + jtb * 32 + col];
        if (interior) *addr = enc; else atomicMax(addr, enc);
      }
      if (g1 > -2.9e38f) {
        const unsigned enc = f2mono(lrelu(g1 + b2v[jtb + 1]));
        unsigned* addr = &gf[b * 128 + (jtb + 1) * 32 + col];
        if (interior) *addr = enc; else atomicMax(addr, enc);
      }
    }
  };

  // fp16 2-term decompose of the 7 inputs -> B1 fragment (bias slots folded)
  auto DECOMP = [&](float mu0, float mu1, float mu2, const f32x4& c4) -> half8 {
    float in[7];
    in[0] = mu0; in[1] = mu1; in[2] = mu2;
    in[3] = c4.x; in[4] = c4.y; in[5] = c4.z; in[6] = c4.w;
    const unsigned pA0 = pkrtz(in[0], in[1]);
    const unsigned pA1 = pkrtz(in[2], in[3]);
    const unsigned pA2 = pkrtz(in[4], in[5]);
    const half2v hA0 = __builtin_bit_cast(half2v, pA0);
    const half2v hA1 = __builtin_bit_cast(half2v, pA1);
    const half2v hA2 = __builtin_bit_cast(half2v, pA2);
    const float xl0 = in[0] - (float)hA0[0];
    const unsigned pA3 = pkrtz(in[6], xl0);
    const half2v hA3 = __builtin_bit_cast(half2v, pA3);
    const unsigned pB0 = pkrtz(in[1] - (float)hA0[1], in[2] - (float)hA1[0]);
    const unsigned pB1 = pkrtz(in[3] - (float)hA1[1], in[4] - (float)hA2[0]);
    const unsigned pB2 = pkrtz(in[5] - (float)hA2[1], in[6] - (float)hA3[0]);
    const unsigned pB3 = 0x3C003C00u;  // (1.0, 1.0) bias slots
    u32x4 bu;
    bu[0] = kh2 ? pB0 : pA0;
    bu[1] = kh2 ? pB1 : pA1;
    bu[2] = kh2 ? pB2 : pA2;
    bu[3] = kh2 ? pB3 : pA3;
    return ash8(bu);
  };

  // pack layer1 outputs + permlane-swap into 4 layer2 A-fragments
  auto MKAFRAG = [&](const f32x16& a0, const f32x16& a1, half8* Afr) {
    unsigned pk0[8], pk1[8];
    #pragma unroll
    for (int q = 0; q < 4; ++q) {
      pk0[2 * q]     = lrelu_pk(a0[4 * q],     a0[4 * q + 1]);
      pk0[2 * q + 1] = lrelu_pk(a0[4 * q + 2], a0[4 * q + 3]);
      pk1[2 * q]     = lrelu_pk(a1[4 * q],     a1[4 * q + 1]);
      pk1[2 * q + 1] = lrelu_pk(a1[4 * q + 2], a1[4 * q + 3]);
    }
    #pragma unroll
    for (int ks = 0; ks < 4; ++ks) {
      const unsigned* s = (ks < 2) ? pk0 : pk1;
      const int base = (ks & 1) * 4;
      unsigned x0 = s[base + 0], y0 = s[base + 2];
      unsigned x1 = s[base + 1], y1 = s[base + 3];
      plswap(x0, y0);
      plswap(x1, y1);
      u32x4 au;
      au[0] = x0; au[1] = x1; au[2] = y0; au[3] = y1;
      Afr[ks] = ash8(au);
    }
  };

  // layer2 + running seg-max for one 32-pt tile, in two j-half passes
  // (acc = 2 x f32x16 = 32 AGPRs live instead of 64)
  auto L2SEG = [&](const half8* Afr, int bi) {
    const int bA = __shfl(bi, 0);
    const int bB = __shfl(bi, 31);
    if (bA != run_b) {
      FLUSH2(run_b, 0, run_s[0], run_s[1]);
      FLUSH2(run_b, 2, run_s[2], run_s[3]);
      #pragma unroll
      for (int jt = 0; jt < 4; ++jt) run_s[jt] = -3.0e38f;
      run_b = bA;
    }
    const bool fast = (bA == bB);
    // precompute boundary info once (wave-uniform)
    int split = 0, bS = 0;
    if (!fast) {
      const unsigned long long ball = __ballot(bi == bA);
      split = (int)__popcll(ball & 0xffffffffULL);
      bS = __shfl(bi, split);
    }

    #pragma unroll
    for (int jh = 0; jh < 2; ++jh) {
      const int jt0 = jh * 2, jt1 = jh * 2 + 1;
      f32x16 a0, a1;
      #pragma unroll
      for (int ks = 0; ks < 4; ++ks) {
        const int kcb = (2 * ks + kh2) * 128;
        const half8 B0 = *(const half8*)&w2f[(kcb + jt0 * 32 + col) * 8];
        const half8 B1 = *(const half8*)&w2f[(kcb + jt1 * 32 + col) * 8];
        a0 = __builtin_amdgcn_mfma_f32_32x32x16_f16(Afr[ks], B0, (ks == 0) ? zf : a0, 0, 0, 0);
        a1 = __builtin_amdgcn_mfma_f32_32x32x16_f16(Afr[ks], B1, (ks == 0) ? zf : a1, 0, 0, 0);
      }

      if (fast) {
        run_s[jt0] = fmaxf(run_s[jt0], max16(a0));
        run_s[jt1] = fmaxf(run_s[jt1], max16(a1));
      } else if (bS == bB) {
        // exactly two batches: uniform-split masked maxes
        float mA0 = -3.0e38f, mA1 = -3.0e38f, mB0 = -3.0e38f, mB1 = -3.0e38f;
        #pragma unroll
        for (int r = 0; r < 16; ++r) {
          const int rr = (r & 3) + ((r >> 2) << 3) + (kh2 << 2);
          const bool inA = rr < split;
          const float v0 = a0[r], v1 = a1[r];
          mA0 = fmaxf(mA0, inA ? v0 : -3.0e38f);
          mA1 = fmaxf(mA1, inA ? v1 : -3.0e38f);
          mB0 = fmaxf(mB0, inA ? -3.0e38f : v0);
          mB1 = fmaxf(mB1, inA ? -3.0e38f : v1);
        }
        FLUSH2(bA, jt0, fmaxf(mA0, run_s[jt0]), fmaxf(mA1, run_s[jt1]));
        run_s[jt0] = mB0;
        run_s[jt1] = mB1;
      } else {
        // >=3 batches in one 32-tile (rare): general loop
        int pbi[16];
        #pragma unroll
        for (int r = 0; r < 16; ++r) {
          const int rr = (r & 3) + ((r >> 2) << 3) + (kh2 << 2);
          pbi[r] = __shfl(bi, rr);
        }
        for (int b = bA; b <= bB; ++b) {
          float m0 = -3.0e38f, m1 = -3.0e38f;
          #pragma unroll
          for (int r = 0; r < 16; ++r)
            if (pbi[r] == b) { m0 = fmaxf(m0, a0[r]); m1 = fmaxf(m1, a1[r]); }
          if (b == bA) { m0 = fmaxf(m0, run_s[jt0]); m1 = fmaxf(m1, run_s[jt1]); }
          if (b < bB) {
            FLUSH2(b, jt0, m0, m1);
          } else {
            run_s[jt0] = m0;
            run_s[jt1] = m1;
          }
        }
      }
    }
    if (!fast) run_b = bB;
  };

  // ---- input pipeline prologue (pair 0) ----
  int pA = min(start + col, N - 1);
  int pB = min(start + 32 + col, N - 1);
  int biA_n = bidx[pA], biB_n = bidx[pB];
  float muA_n[3] = {muons[pA * 3], muons[pA * 3 + 1], muons[pA * 3 + 2]};
  float muB_n[3] = {muons[pB * 3], muons[pB * 3 + 1], muons[pB * 3 + 2]};
  f32x4 c4A_n = *(const f32x4*)&cond[biA_n * 4];
  f32x4 c4B_n = *(const f32x4*)&cond[biB_n * 4];

  for (int pbase = start; pbase < end; pbase += 64) {
    const int biA = biA_n, biB = biB_n;
    const float mA0 = muA_n[0], mA1 = muA_n[1], mA2 = muA_n[2];
    const float mB0 = muB_n[0], mB1 = muB_n[1], mB2 = muB_n[2];
    const f32x4 c4A = c4A_n, c4B = c4B_n;

    // issue next pair's independent loads NOW
    const int pnA = min(pbase + 64 + col, N - 1);
    const int pnB = min(pbase + 96 + col, N - 1);
    biA_n = bidx[pnA]; biB_n = bidx[pnB];
    muA_n[0] = muons[pnA * 3]; muA_n[1] = muons[pnA * 3 + 1]; muA_n[2] = muons[pnA * 3 + 2];
    muB_n[0] = muons[pnB * 3]; muB_n[1] = muons[pnB * 3 + 1]; muB_n[2] = muons[pnB * 3 + 2];

    // ---- decompose + layer1 for BOTH tiles (independent MFMA chains) ----
    const half8 bfrA = DECOMP(mA0, mA1, mA2, c4A);
    const half8 bfrB = DECOMP(mB0, mB1, mB2, c4B);
    const f32x16 aA0 = __builtin_amdgcn_mfma_f32_32x32x16_f16(a1lo, bfrA, zf, 0, 0, 0);
    const f32x16 aA1 = __builtin_amdgcn_mfma_f32_32x32x16_f16(a1hi, bfrA, zf, 0, 0, 0);
    const f32x16 aB0 = __builtin_amdgcn_mfma_f32_32x32x16_f16(a1lo, bfrB, zf, 0, 0, 0);
    const f32x16 aB1 = __builtin_amdgcn_mfma_f32_32x32x16_f16(a1hi, bfrB, zf, 0, 0, 0);

    // dependent cond gathers for next pair (bi*_n arrived by now)
    c4A_n = *(const f32x4*)&cond[biA_n * 4];
    c4B_n = *(const f32x4*)&cond[biB_n * 4];

    // ---- pack + swap both tiles ----
    half8 AfrA[4], AfrB[4];
    MKAFRAG(aA0, aA1, AfrA);
    MKAFRAG(aB0, aB1, AfrB);

    // ---- layer2 + seg-max, tile A then tile B (acc regs reused) ----
    L2SEG(AfrA, biA);
    L2SEG(AfrB, biB);
  }
  FLUSH2(run_b, 0, run_s[0], run_s[1]);
  FLUSH2(run_b, 2, run_s[2], run_s[3]);
}

// ---- decision MLP via 3-term split-fp16 MFMA: [B,132+bias] @ W3 -> lrelu -> .W4 + b4 ----
// Per wave: 32 batch rows. A = W3 hi/lo frags in LDS (b3 folded at k-slot 132,
// K padded to 144 = 9 chunks); B = din from gf (mono decode -> hi/lo fp16).
// __launch_bounds__(256,2): live state ~170 regs; default allocator would spill.
__global__ __launch_bounds__(256, 2) void sc_final(
    const unsigned* __restrict__ gf, const float* __restrict__ cond,
    const float* __restrict__ W3, const float* __restrict__ b3,
    const float* __restrict__ W4, const float* __restrict__ b4,
    float* __restrict__ out, int B) {
  __shared__ __align__(16) _Float16 w3h[18432];  // [h=k>>3 (18)][j (128)][e=k&7 (8)]
  __shared__ __align__(16) _Float16 w3l[18432];
  __shared__ float w4s[128];
  const int t = threadIdx.x;
  const int w = t >> 6, lane = t & 63, col = lane & 31, kh2 = lane >> 5;

  for (int i = t; i < 144 * 128; i += 256) {
    const int k = i >> 7, j = i & 127;
    float v = 0.0f;
    if (k < 132) v = W3[k * 128 + j];
    else if (k == 132) v = b3[j];
    const _Float16 h = (_Float16)v;
    const int a = ((k >> 3) * 128 + j) * 8 + (k & 7);
    w3h[a] = h;
    w3l[a] = (_Float16)(v - (float)h);
  }
  if (t < 128) w4s[t] = W4[t];
  __syncthreads();

  const int tile = blockIdx.x * 4 + w;
  const int row = tile * 32 + col;
  const int rc = min(row, B - 1);

  // all gf data for this row's k-half: 16 x dwordx4, issued upfront
  uint4 g[16];
  #pragma unroll
  for (int kc = 0; kc < 8; ++kc) {
    const int base = rc * 128 + kc * 16 + kh2 * 8;
    g[2 * kc]     = *(const uint4*)&gf[base];
    g[2 * kc + 1] = *(const uint4*)&gf[base + 4];
  }
  const f32x4 c4 = *(const f32x4*)&cond[rc * 4];

  f32x16 zf;
  #pragma unroll
  for (int e = 0; e < 16; ++e) zf[e] = 0.0f;
  f32x16 acc[4];

  #pragma unroll
  for (int kc = 0; kc < 9; ++kc) {
    float v[8];
    if (kc < 8) {
      const uint4 ga = g[2 * kc], gb = g[2 * kc + 1];
      v[0] = mono2f(ga.x); v[1] = mono2f(ga.y); v[2] = mono2f(ga.z); v[3] = mono2f(ga.w);
      v[4] = mono2f(gb.x); v[5] = mono2f(gb.y); v[6] = mono2f(gb.z); v[7] = mono2f(gb.w);
    } else if (kh2 == 0) {
      v[0] = c4.x; v[1] = c4.y; v[2] = c4.z; v[3] = c4.w;
      v[4] = 1.0f; v[5] = 0.0f; v[6] = 0.0f; v[7] = 0.0f;  // k=132 -> b3 slot
    } else {
      #pragma unroll
      for (int e = 0; e < 8; ++e) v[e] = 0.0f;
    }
    u32x4 bh, bl;
    #pragma unroll
    for (int q = 0; q < 4; ++q) {
      const unsigned ph = pkrtz(v[2 * q], v[2 * q + 1]);
      const half2v hh = __builtin_bit_cast(half2v, ph);
      bh[q] = ph;
      bl[q] = pkrtz(v[2 * q] - (float)hh[0], v[2 * q + 1] - (float)hh[1]);
    }
    const half8 Bh = ash8(bh), Bl = ash8(bl);
    #pragma unroll
    for (int jt = 0; jt < 4; ++jt) {
      const int a = ((kc * 2 + kh2) * 128 + jt * 32 + col) * 8;
      const half8 Ah = *(const half8*)&w3h[a];
      const half8 Al = *(const half8*)&w3l[a];
      f32x16 c = (kc == 0) ? zf : acc[jt];
      c = __builtin_amdgcn_mfma_f32_32x32x16_f16(Ah, Bh, c, 0, 0, 0);
      c = __builtin_amdgcn_mfma_f32_32x32x16_f16(Ah, Bl, c, 0, 0, 0);
      c = __builtin_amdgcn_mfma_f32_32x32x16_f16(Al, Bh, c, 0, 0, 0);
      acc[jt] = c;
    }
  }

  // h3 -> lrelu -> dot W4 over this lane's kh2 j-half
  float partial = 0.0f;
  #pragma unroll
  for (int jt = 0; jt < 4; ++jt)
    #pragma unroll
    for (int r = 0; r < 16; ++r) {
      const int j = jt * 32 + (r & 3) + ((r >> 2) << 3) + (kh2 << 2);
      partial += lrelu(acc[jt][r]) * w4s[j];
    }
  unsigned pa = __float_as_uint(partial), pb = pa;
  plswap(pa, pb);
  const float tot = __uint_as_float(pa) + __uint_as_float(pb);
  if (lane < 32 && row < B) out[row] = tot + b4[0];
}

extern "C" void kernel_launch(void* const* d_in, const int* in_sizes, int n_in,
                              void* d_out, int out_size, void* d_ws, size_t ws_size,
                              hipStream_t stream) {
  const float* muons = (const float*)d_in[0];
  const int* bidx = (const int*)d_in[1];
  const float* cond = (const float*)d_in[2];
  const float* W1 = (const float*)d_in[4];
  const float* b1 = (const float*)d_in[5];
  const float* W2 = (const float*)d_in[6];
  const float* b2 = (const float*)d_in[7];
  const float* W3 = (const float*)d_in[8];
  const float* b3 = (const float*)d_in[9];
  const float* W4 = (const float*)d_in[10];
  const float* b4 = (const float*)d_in[11];
  float* out = (float*)d_out;
  const int N = in_sizes[1];
  const int B = out_size;
  unsigned* gf = (unsigned*)d_ws;  // B*128 mono-encoded uints (8 MB)

  const int total4 = (B * 128) / 4;
  sc_init<<<(total4 + 255) / 256, 256, 0, stream>>>(gf, total4);

  const int nblocks = 2048;
  const int nwaves = nblocks * 4;
  const int cpw = (((N + nwaves - 1) / nwaves) + 63) & ~63;  // points per wave, ×64
  sc_main<<<nblocks, 256, 0, stream>>>(muons, bidx, cond, W1, b1, W2, b2, gf, N, cpw);

  const int ftiles = (B + 31) / 32;
  const int fblocks = (ftiles + 3) / 4;
  sc_final<<<fblocks, 256, 0, stream>>>(gf, cond, W3, b3, W4, b4, out, B);
  (void)n_in; (void)ws_size;
}